// Round 14
// baseline (240.175 us; speedup 1.0000x reference)
//
#include <hip/hip_runtime.h>
#include <hip/hip_bf16.h>

typedef unsigned short u16;
typedef unsigned int u32;
typedef __bf16 bf16x8 __attribute__((ext_vector_type(8)));
typedef float f32x4 __attribute__((ext_vector_type(4)));

#define AS1(p) ((const __attribute__((address_space(1))) void*)(p))
#define AS3(p) ((__attribute__((address_space(3))) void*)(p))

#define TOK   256
#define CDIM  512
#define QKVC  1536
#define LOG2E 1.4426950408889634f
#define QSCALE (0.17677669529663687f * 1.4426950408889634f)  // D^-0.5 * log2e

__device__ __forceinline__ u16 f2b(float f) {
  unsigned u = __float_as_uint(f);
  unsigned r = (u + 0x7fffu + ((u >> 16) & 1u)) >> 16;
  return (u16)r;
}
__device__ __forceinline__ u16 f2bc(float f) {
  __bf16 h = (__bf16)f;
  u16 u;
  __builtin_memcpy(&u, &h, 2);
  return u;
}
__device__ __forceinline__ float bf_lo(u32 wd) { return __uint_as_float(wd << 16); }
__device__ __forceinline__ float bf_hi(u32 wd) { return __uint_as_float(wd & 0xffff0000u); }
__device__ __forceinline__ float ex2(float x) {
  float r;
  asm("v_exp_f32 %0, %1" : "=v"(r) : "v"(x));
  return r;
}

// ---------------- fp32 -> bf16 conversion (weights only) ----------------
__global__ __launch_bounds__(256) void cvt_bf16_kernel(const float* __restrict__ in,
                                                       u16* __restrict__ out, int n) {
  int i = (blockIdx.x * 256 + threadIdx.x) * 8;
  if (i >= n) return;
  float4 a = *(const float4*)(in + i);
  float4 b = *(const float4*)(in + i + 4);
  u16 h[8];
  h[0] = f2b(a.x); h[1] = f2b(a.y); h[2] = f2b(a.z); h[3] = f2b(a.w);
  h[4] = f2b(b.x); h[5] = f2b(b.y); h[6] = f2b(b.z); h[7] = f2b(b.w);
  *(uint4*)(out + i) = *(const uint4*)h;
}

// ---------------- bias2: S^T fragment layout, bf16, pre-multiplied by log2e ----------------
__global__ __launch_bounds__(256) void build_bias2_kernel(const float* __restrict__ rpb,
                                                          u16* __restrict__ bias2) {
  int i = blockIdx.x * 256 + threadIdx.x;   // 16*16*64*64 = 2^20
  int tr = i & 63, lane = (i >> 6) & 63, rb = (i >> 12) & 15, h = i >> 16;
  int t = tr >> 2, r = tr & 3;
  int n = rb * 16 + (lane & 15);
  int m = t * 16 + (lane >> 4) * 4 + r;
  int idx = ((n >> 4) - (m >> 4) + 15) * 31 + ((n & 15) - (m & 15) + 15);
  bias2[i] = f2b(rpb[idx * 16 + h] * LOG2E);
}

// ---------------- mod2: S^T fragment layout, bf16 ----------------
__global__ __launch_bounds__(256) void build_mod2_kernel(u16* __restrict__ mod2) {
  int i = blockIdx.x * 256 + threadIdx.x;   // 16*64*64 = 65536
  int tr = i & 63, lane = (i >> 6) & 63, rb = i >> 12;
  int t = tr >> 2, r = tr & 3;
  int n = rb * 16 + (lane & 15);
  int m = t * 16 + (lane >> 4) * 4 + r;
  int dr = (n >> 4) - (m >> 4), dc = (n & 15) - (m & 15);
  int d2 = dr * dr + dc * dc;
  float val = 0.0f;
  if (d2 <= 229) {   // exact integer form of (m >= bound); boundary at d2==229
    const float fc = 6.2831853071795864f / (60.0f * 1.4142135623730951f);
    val = expf(cosf(fc * sqrtf((float)d2))) * 0.5f;
  }
  mod2[i] = f2b(val);
}

// ---------------- bf16 GEMM: out = A[M,K] @ Bt[N,K]^T + bias ----------------
// MODE 0: BM=128, 256 thr; A = x fp32 (reg-stage + cvt), B gload_lds; BOTH double-
//         buffered -> ONE barrier per K-step (stage of k+1 issued before compute of k,
//         drained by the end-of-step barrier). LDS-bounce epilogue -> qfrag/kfrag/vsw.
// MODE 1: BM=128, 256 thr, single-buffer 2-barrier (unchanged, latency-fine); f32 out.
template<int MODE>
__global__ __launch_bounds__(256, 2) void gemm_bt(
    const float* __restrict__ Ax, const u16* __restrict__ A,
    const u16* __restrict__ Bt, const float* __restrict__ bvec,
    u16* __restrict__ oq, u16* __restrict__ ok, u16* __restrict__ ov,
    float* __restrict__ of) {
  constexpr int K = 512;
  constexpr int NBN = (MODE == 0) ? 12 : 4;
  constexpr int PER_XCD = (MODE == 0) ? 384 : 128;
  __shared__ __align__(16) u16 SM[(MODE == 0) ? 32768 : 16384];
  u16* As0 = SM;                      // 16KB tiles
  u16* Bs0 = SM + 8192;
  u16* As1 = (MODE == 0) ? (SM + 16384) : As0;
  u16* Bs1 = (MODE == 0) ? (SM + 24576) : Bs0;
  const int tid = threadIdx.x, lane = tid & 63, w = tid >> 6;
  const int wr = w >> 1, wc = w & 1, lr = lane & 15, lg = lane >> 4;
  // XCD-chunked 1-D grid: bm-pair x all-bn contiguous per XCD (A+B L2-resident)
  const int logical = (blockIdx.x & 7) * PER_XCD + (blockIdx.x >> 3);
  const int bm = (logical / (2 * NBN)) * 2 + (logical & 1);
  const int bn = (logical % (2 * NBN)) >> 1;
  const u16* Bg = Bt + (size_t)bn * 128 * K;
  f32x4 acc[4][4];
#pragma unroll
  for (int m = 0; m < 4; ++m)
#pragma unroll
    for (int n = 0; n < 4; ++n) acc[m][n] = (f32x4){0.f, 0.f, 0.f, 0.f};

  if (MODE == 0) {
    const float* Abase = Ax + (size_t)(bm * 128) * K;
    float4 pa0[4], pa1[4];
    // prologue: A(0) -> regs, B(0) -> Bs0, A(0) cvt -> As0
#pragma unroll
    for (int it = 0; it < 4; ++it) {
      int chunk = it * 256 + tid;
      int r = chunk >> 3, gg = (chunk & 7) ^ (r & 7);
      const float* src = Abase + (size_t)r * K + gg * 8;
      pa0[it] = *(const float4*)src;
      pa1[it] = *(const float4*)(src + 4);
    }
#pragma unroll
    for (int it = 0; it < 4; ++it) {
      int chunk = it * 256 + tid;
      int r = chunk >> 3, kcs = (chunk & 7) ^ (r & 7);
      __builtin_amdgcn_global_load_lds(AS1(Bg + (size_t)r * K + kcs * 8),
                                       AS3(Bs0 + chunk * 8), 16, 0, 0);
    }
#pragma unroll
    for (int it = 0; it < 4; ++it) {
      int chunk = it * 256 + tid;
      u16 hb[8];
      hb[0] = f2bc(pa0[it].x); hb[1] = f2bc(pa0[it].y);
      hb[2] = f2bc(pa0[it].z); hb[3] = f2bc(pa0[it].w);
      hb[4] = f2bc(pa1[it].x); hb[5] = f2bc(pa1[it].y);
      hb[6] = f2bc(pa1[it].z); hb[7] = f2bc(pa1[it].w);
      *(uint4*)(As0 + chunk * 8) = *(const uint4*)hb;
    }
    __syncthreads();

#pragma unroll
    for (int ks = 0; ks < 8; ++ks) {
      u16* Ac = (ks & 1) ? As1 : As0;
      u16* Bc = (ks & 1) ? Bs1 : Bs0;
      u16* An = (ks & 1) ? As0 : As1;
      u16* Bn = (ks & 1) ? Bs0 : Bs1;
      // stage k+1: issue BEFORE compute; drains at the end-of-step barrier
      if (ks < 7) {
        const int kn = (ks + 1) * 64;
#pragma unroll
        for (int it = 0; it < 4; ++it) {
          int chunk = it * 256 + tid;
          int r = chunk >> 3, kcs = (chunk & 7) ^ (r & 7);
          __builtin_amdgcn_global_load_lds(AS1(Bg + (size_t)r * K + kn + kcs * 8),
                                           AS3(Bn + chunk * 8), 16, 0, 0);
        }
#pragma unroll
        for (int it = 0; it < 4; ++it) {
          int chunk = it * 256 + tid;
          int r = chunk >> 3, gg = (chunk & 7) ^ (r & 7);
          const float* src = Abase + (size_t)r * K + kn + gg * 8;
          pa0[it] = *(const float4*)src;
          pa1[it] = *(const float4*)(src + 4);
        }
      }
      // compute on buf[cur]
#pragma unroll
      for (int kk = 0; kk < 2; ++kk) {
        bf16x8 a[4], b[4];
#pragma unroll
        for (int m = 0; m < 4; ++m) {
          int ar = wr * 64 + m * 16 + lr;
          a[m] = *(const bf16x8*)&Ac[ar * 64 + (((kk * 4 + lg) ^ (lr & 7)) << 3)];
        }
#pragma unroll
        for (int n = 0; n < 4; ++n) {
          int br = wc * 64 + n * 16 + lr;
          b[n] = *(const bf16x8*)&Bc[br * 64 + (((kk * 4 + lg) ^ (lr & 7)) << 3)];
        }
#pragma unroll
        for (int m = 0; m < 4; ++m)
#pragma unroll
          for (int n = 0; n < 4; ++n)
            acc[m][n] = __builtin_amdgcn_mfma_f32_16x16x32_bf16(a[m], b[n], acc[m][n], 0, 0, 0);
      }
      // A(k+1): cvt + write into buf^1 (no hazard with this step's reads)
      if (ks < 7) {
#pragma unroll
        for (int it = 0; it < 4; ++it) {
          int chunk = it * 256 + tid;
          u16 hb[8];
          hb[0] = f2bc(pa0[it].x); hb[1] = f2bc(pa0[it].y);
          hb[2] = f2bc(pa0[it].z); hb[3] = f2bc(pa0[it].w);
          hb[4] = f2bc(pa1[it].x); hb[5] = f2bc(pa1[it].y);
          hb[6] = f2bc(pa1[it].z); hb[7] = f2bc(pa1[it].w);
          *(uint4*)(An + chunk * 8) = *(const uint4*)hb;
        }
      }
      __syncthreads();   // ONE barrier per K-step: drains A ds_writes + B gload_lds
    }
  } else {
    const u16* Ag = A + (size_t)bm * 128 * K;
    for (int k0 = 0; k0 < K; k0 += 64) {
#pragma unroll
      for (int it = 0; it < 4; ++it) {
        int chunk = it * 256 + tid;
        int r = chunk >> 3, kcs = (chunk & 7) ^ (r & 7);
        __builtin_amdgcn_global_load_lds(AS1(Ag + (size_t)r * K + k0 + kcs * 8),
                                         AS3(As0 + chunk * 8), 16, 0, 0);
        __builtin_amdgcn_global_load_lds(AS1(Bg + (size_t)r * K + k0 + kcs * 8),
                                         AS3(Bs0 + chunk * 8), 16, 0, 0);
      }
      __syncthreads();
#pragma unroll
      for (int kk = 0; kk < 2; ++kk) {
        bf16x8 a[4], b[4];
#pragma unroll
        for (int m = 0; m < 4; ++m) {
          int ar = wr * 64 + m * 16 + lr;
          a[m] = *(const bf16x8*)&As0[ar * 64 + (((kk * 4 + lg) ^ (lr & 7)) << 3)];
        }
#pragma unroll
        for (int n = 0; n < 4; ++n) {
          int br = wc * 64 + n * 16 + lr;
          b[n] = *(const bf16x8*)&Bs0[br * 64 + (((kk * 4 + lg) ^ (lr & 7)) << 3)];
        }
#pragma unroll
        for (int m = 0; m < 4; ++m)
#pragma unroll
          for (int n = 0; n < 4; ++n)
            acc[m][n] = __builtin_amdgcn_mfma_f32_16x16x32_bf16(a[m], b[n], acc[m][n], 0, 0, 0);
      }
      __syncthreads();
    }
  }

  if (MODE == 1) {
#pragma unroll
    for (int m = 0; m < 4; ++m)
#pragma unroll
      for (int n = 0; n < 4; ++n)
#pragma unroll
        for (int r = 0; r < 4; ++r) {
          int row = bm * 128 + wr * 64 + m * 16 + lg * 4 + r;
          int col = bn * 128 + wc * 64 + n * 16 + lr;
          of[(size_t)row * CDIM + col] = acc[m][n][r] + bvec[col];
        }
    return;
  }

  // ---- MODE 0 epilogue: bounce via per-wave swizzled 64x64 bf16 LDS tile ----
  const int typ = bn >> 2;                 // 0=Q, 1=K, 2=V
  const int col0 = bn * 128 + wc * 64;
  const int row0 = bm * 128 + wr * 64;
  char* Tb = (char*)SM + w * 8192;         // 8 KB per wave (staging dead)

#pragma unroll
  for (int n = 0; n < 4; ++n) {
    float bv = bvec[col0 + n * 16 + lr];
#pragma unroll
    for (int m = 0; m < 4; ++m)
#pragma unroll
      for (int r = 0; r < 4; ++r) {
        float v = acc[m][n][r] + bv;
        if (typ == 0) v *= QSCALE;
        int row_l, col_l;
        if (typ < 2) { row_l = m * 16 + lg * 4 + r; col_l = n * 16 + lr; }
        else         { row_l = n * 16 + lr;         col_l = m * 16 + lg * 4 + r; }  // V: transposed
        int byte = row_l * 128 + ((((col_l >> 3) ^ (row_l & 7)) << 4) | ((col_l & 7) << 1));
        *(u16*)(Tb + byte) = f2b(v);
      }
  }
  asm volatile("" ::: "memory");   // pin LDS write->read order (strict-aliasing guard)
  if (typ < 2) {
    int tok = row0 + lane;
    int tokb = tok >> 8;
    u16* obase = (typ == 0) ? oq : ok;
#pragma unroll
    for (int G = 0; G < 8; ++G) {
      int hl = G >> 2, q = G & 3;
      uint4 v = *(const uint4*)(Tb + lane * 128 + ((G ^ (lane & 7)) << 4));
      int hh = ((col0 >> 5) & 15) + hl;     // head index
      size_t a = ((((size_t)tokb * 16 + hh) * 16 + ((tok >> 4) & 15)) * 64 +
                  ((tok & 15) | (q << 4))) * 8;
      *(uint4*)(obase + a) = v;
    }
  } else {
    int tl0 = row0 & 255, tokb = row0 >> 8;
    int hl = lane >> 5, t = (lane >> 3) & 3, c = lane & 7;
    int hh = ((col0 >> 5) & 15) + hl;       // head index
#pragma unroll
    for (int i = 0; i < 8; ++i) {
      int d = i * 4 + t;
      uint4 v = *(const uint4*)(Tb + (hl * 32 + d) * 128 + (c << 4));
      size_t a = (((size_t)tokb * 16 + hh) * 32 + d) * 256 + tl0 + c * 8;
      *(uint4*)(ov + a) = v;
    }
  }
}

// ---------------- fused attention: 512-thread block = (b, h, qpair), 8 waves ----------------
__global__ __launch_bounds__(512, 4) void attn_kernel(const u16* __restrict__ qfrag,
                                                      const u16* __restrict__ kfrag,
                                                      const u16* __restrict__ vsw,
                                                      const u16* __restrict__ bias2,
                                                      const u16* __restrict__ mod2,
                                                      u16* __restrict__ attnout) {
  __shared__ __align__(16) u16 SM[24576];
  const int logical = (blockIdx.x & 7) * 512 + (blockIdx.x >> 3);   // 4096 blocks
  const int h = logical >> 8;           // 2 heads per XCD (bias/mod L2-resident)
  const int b = (logical >> 1) & 127;   // qpair-adjacent -> K/V L2 reuse
  const int qpair = logical & 1;
  const int tid = threadIdx.x, lane = tid & 63, w = tid >> 6;
  const int lr = lane & 15, lg = lane >> 4;
  const int rb = qpair * 8 + w;         // this wave's row-block (16 q rows)
  const int bhid = b * 16 + h;

  const u16* kg = kfrag + (size_t)bhid * 8192;
  const u16* vg = vsw + (size_t)bhid * 8192;
#pragma unroll
  for (int it = 0; it < 2; ++it) {
    __builtin_amdgcn_global_load_lds(AS1(kg + (it * 512 + tid) * 8),
                                     AS3(SM + (it * 512 + tid) * 8), 16, 0, 0);
    __builtin_amdgcn_global_load_lds(AS1(vg + (it * 512 + tid) * 8),
                                     AS3(SM + 8192 + (it * 512 + tid) * 8), 16, 0, 0);
  }
  bf16x8 qf = *(const bf16x8*)(qfrag + ((size_t)bhid * 16 + rb) * 512 + lane * 8);
  __syncthreads();

  const u16* bias_base = bias2 + (((size_t)h * 16 + rb) * 64 + lane) * 64;
  const u16* mod_base  = mod2 + ((size_t)rb * 64 + lane) * 64;
  char* Pbase = (char*)SM + 32768 + w * 2048;
  const char* Vb = (const char*)(SM + 8192);

  // S^T = K Q^T + bias : full 16 tiles, per-quarter transient bias loads
  f32x4 s[16];
#pragma unroll
  for (int q = 0; q < 4; ++q) {
    u32 bw8[8];
    {
      const uint4* bp = (const uint4*)(bias_base + q * 16);
      *(uint4*)&bw8[0] = bp[0]; *(uint4*)&bw8[4] = bp[1];
    }
#pragma unroll
    for (int tl = 0; tl < 4; ++tl) {
      int t = q * 4 + tl;
      bf16x8 kf = *(const bf16x8*)(SM + (t * 64 + lane) * 8);
      f32x4 c;
      c[0] = bf_lo(bw8[tl * 2]);     c[1] = bf_hi(bw8[tl * 2]);
      c[2] = bf_lo(bw8[tl * 2 + 1]); c[3] = bf_hi(bw8[tl * 2 + 1]);
      s[t] = __builtin_amdgcn_mfma_f32_16x16x32_bf16(kf, qf, c, 0, 0, 0);
    }
  }

  // softmax over m (log2 domain): 4 parallel max chains + 2 shuffles
  float mr0 = s[0][0], mr1 = s[0][1], mr2 = s[0][2], mr3 = s[0][3];
#pragma unroll
  for (int t = 1; t < 16; ++t) {
    mr0 = fmaxf(mr0, s[t][0]); mr1 = fmaxf(mr1, s[t][1]);
    mr2 = fmaxf(mr2, s[t][2]); mr3 = fmaxf(mr3, s[t][3]);
  }
  float mx = fmaxf(fmaxf(mr0, mr1), fmaxf(mr2, mr3));
  mx = fmaxf(mx, __shfl_xor(mx, 16, 64));
  mx = fmaxf(mx, __shfl_xor(mx, 32, 64));
  float s0 = 0.f, s1 = 0.f, s2 = 0.f, s3 = 0.f;
#pragma unroll
  for (int t = 0; t < 16; ++t) {
    s[t][0] = ex2(s[t][0] - mx); s0 += s[t][0];
    s[t][1] = ex2(s[t][1] - mx); s1 += s[t][1];
    s[t][2] = ex2(s[t][2] - mx); s2 += s[t][2];
    s[t][3] = ex2(s[t][3] - mx); s3 += s[t][3];
  }
  float sm = (s0 + s1) + (s2 + s3);
  sm += __shfl_xor(sm, 16, 64);
  sm += __shfl_xor(sm, 32, 64);
  sm = __builtin_amdgcn_rcpf(sm);   // own-lane: denominator for query n = lr (pre-pack norm)

  // quarter-partitioned pack (normalized P, mod applied) + PV
  f32x4 o0 = (f32x4){0.f, 0.f, 0.f, 0.f};
  f32x4 o1 = (f32x4){0.f, 0.f, 0.f, 0.f};
#pragma unroll
  for (int q = 0; q < 4; ++q) {
    u32 mw8[8];
    {
      const uint4* mp = (const uint4*)(mod_base + q * 16);
      *(uint4*)&mw8[0] = mp[0]; *(uint4*)&mw8[4] = mp[1];
    }
#pragma unroll
    for (int tl = 0; tl < 4; ++tl) {
      int t = q * 4 + tl;
      u16 pk[4];
#pragma unroll
      for (int r = 0; r < 4; ++r) {
        u32 wd = mw8[tl * 2 + (r >> 1)];
        float mf = (r & 1) ? bf_hi(wd) : bf_lo(wd);
        pk[r] = f2bc(s[t][r] * sm * mf);
      }
      int hi2 = (t * 2 + (lg >> 1)) & 3;
      *(uint2*)(Pbase + ((t >> 1) & 1) * 1024 + ((hi2 << 4) | lr) * 16 + (lg & 1) * 8)
          = *(const uint2*)pk;
    }
    asm volatile("" ::: "memory");   // pack stores must precede PV loads
#pragma unroll
    for (int kl = 0; kl < 2; ++kl) {
      bf16x8 pa = *(const bf16x8*)(Pbase + kl * 1024 + lane * 16);
      int cv = ((q * 2 + kl) * 4 + lg) ^ (lr & 7);
      bf16x8 v0 = *(const bf16x8*)(Vb + lr * 512 + cv * 16);
      bf16x8 v1 = *(const bf16x8*)(Vb + (16 + lr) * 512 + cv * 16);
      o0 = __builtin_amdgcn_mfma_f32_16x16x32_bf16(pa, v0, o0, 0, 0, 0);
      o1 = __builtin_amdgcn_mfma_f32_16x16x32_bf16(pa, v1, o1, 0, 0, 0);
    }
    asm volatile("" ::: "memory");   // PV loads must precede next quarter's pack (WAR)
  }

  u16* orow = attnout + (size_t)(b * TOK + rb * 16) * CDIM + h * 32;
#pragma unroll
  for (int r = 0; r < 4; ++r) {
    orow[(size_t)(lg * 4 + r) * CDIM + lr] = f2bc(o0[r]);
    orow[(size_t)(lg * 4 + r) * CDIM + 16 + lr] = f2bc(o1[r]);
  }
}

// ---------------- launch ----------------
extern "C" void kernel_launch(void* const* d_in, const int* in_sizes, int n_in,
                              void* d_out, int out_size, void* d_ws, size_t ws_size,
                              hipStream_t stream) {
  const float* x      = (const float*)d_in[0];
  const float* qkv_w  = (const float*)d_in[1];
  const float* qkv_b  = (const float*)d_in[2];
  const float* proj_w = (const float*)d_in[3];
  const float* proj_b = (const float*)d_in[4];
  const float* rpb    = (const float*)d_in[5];

  char* ws = (char*)d_ws;
  u16* qkvwb  = (u16*)(ws + 33554432);      //  1,572,864 B
  u16* projwb = (u16*)(ws + 35127296);      //    524,288 B
  u16* qfrag  = (u16*)(ws + 35651584);      // 33,554,432 B
  u16* kfrag  = (u16*)(ws + 69206016);      // 33,554,432 B
  u16* vswb   = (u16*)(ws + 102760448);     // 33,554,432 B
  u16* attnb  = (u16*)(ws + 136314880);     // 33,554,432 B
  u16* bias2  = (u16*)(ws + 169869312);     //  2,097,152 B
  u16* mod2   = (u16*)(ws + 171966464);     //    131,072 B

  cvt_bf16_kernel<<<384, 256, 0, stream>>>(qkv_w, qkvwb, 1536 * 512);
  cvt_bf16_kernel<<<128, 256, 0, stream>>>(proj_w, projwb, 512 * 512);
  build_bias2_kernel<<<4096, 256, 0, stream>>>(rpb, bias2);
  build_mod2_kernel<<<256, 256, 0, stream>>>(mod2);

  gemm_bt<0><<<3072, 256, 0, stream>>>(x, nullptr, qkvwb, qkv_b,
                                       qfrag, kfrag, vswb, nullptr);
  attn_kernel<<<4096, 512, 0, stream>>>(qfrag, kfrag, vswb, bias2, mod2, attnb);
  gemm_bt<1><<<1024, 256, 0, stream>>>(nullptr, attnb, projwb, proj_b,
                                       nullptr, nullptr, nullptr, (float*)d_out);
}

// Round 15
// 226.578 us; speedup vs baseline: 1.0600x; 1.0600x over previous
//
#include <hip/hip_runtime.h>
#include <hip/hip_bf16.h>

typedef unsigned short u16;
typedef unsigned int u32;
typedef __bf16 bf16x8 __attribute__((ext_vector_type(8)));
typedef float f32x4 __attribute__((ext_vector_type(4)));

#define AS1(p) ((const __attribute__((address_space(1))) void*)(p))
#define AS3(p) ((__attribute__((address_space(3))) void*)(p))

#define TOK   256
#define CDIM  512
#define QKVC  1536
#define LOG2E 1.4426950408889634f
#define QSCALE (0.17677669529663687f * 1.4426950408889634f)  // D^-0.5 * log2e

__device__ __forceinline__ u16 f2b(float f) {
  unsigned u = __float_as_uint(f);
  unsigned r = (u + 0x7fffu + ((u >> 16) & 1u)) >> 16;
  return (u16)r;
}
__device__ __forceinline__ u16 f2bc(float f) {
  __bf16 h = (__bf16)f;
  u16 u;
  __builtin_memcpy(&u, &h, 2);
  return u;
}
__device__ __forceinline__ float bf_lo(u32 wd) { return __uint_as_float(wd << 16); }
__device__ __forceinline__ float bf_hi(u32 wd) { return __uint_as_float(wd & 0xffff0000u); }
__device__ __forceinline__ float ex2(float x) {
  float r;
  asm("v_exp_f32 %0, %1" : "=v"(r) : "v"(x));
  return r;
}

// ---------------- fp32 -> bf16 conversion (weights only) ----------------
__global__ __launch_bounds__(256) void cvt_bf16_kernel(const float* __restrict__ in,
                                                       u16* __restrict__ out, int n) {
  int i = (blockIdx.x * 256 + threadIdx.x) * 8;
  if (i >= n) return;
  float4 a = *(const float4*)(in + i);
  float4 b = *(const float4*)(in + i + 4);
  u16 h[8];
  h[0] = f2b(a.x); h[1] = f2b(a.y); h[2] = f2b(a.z); h[3] = f2b(a.w);
  h[4] = f2b(b.x); h[5] = f2b(b.y); h[6] = f2b(b.z); h[7] = f2b(b.w);
  *(uint4*)(out + i) = *(const uint4*)h;
}

// ---------------- bias2: S^T fragment layout, bf16, pre-multiplied by log2e ----------------
__global__ __launch_bounds__(256) void build_bias2_kernel(const float* __restrict__ rpb,
                                                          u16* __restrict__ bias2) {
  int i = blockIdx.x * 256 + threadIdx.x;   // 16*16*64*64 = 2^20
  int tr = i & 63, lane = (i >> 6) & 63, rb = (i >> 12) & 15, h = i >> 16;
  int t = tr >> 2, r = tr & 3;
  int n = rb * 16 + (lane & 15);
  int m = t * 16 + (lane >> 4) * 4 + r;
  int idx = ((n >> 4) - (m >> 4) + 15) * 31 + ((n & 15) - (m & 15) + 15);
  bias2[i] = f2b(rpb[idx * 16 + h] * LOG2E);
}

// ---------------- mod2: S^T fragment layout, bf16 ----------------
__global__ __launch_bounds__(256) void build_mod2_kernel(u16* __restrict__ mod2) {
  int i = blockIdx.x * 256 + threadIdx.x;   // 16*64*64 = 65536
  int tr = i & 63, lane = (i >> 6) & 63, rb = i >> 12;
  int t = tr >> 2, r = tr & 3;
  int n = rb * 16 + (lane & 15);
  int m = t * 16 + (lane >> 4) * 4 + r;
  int dr = (n >> 4) - (m >> 4), dc = (n & 15) - (m & 15);
  int d2 = dr * dr + dc * dc;
  float val = 0.0f;
  if (d2 <= 229) {   // exact integer form of (m >= bound); boundary at d2==229
    const float fc = 6.2831853071795864f / (60.0f * 1.4142135623730951f);
    val = expf(cosf(fc * sqrtf((float)d2))) * 0.5f;
  }
  mod2[i] = f2b(val);
}

// ---------------- bf16 GEMM: out = A[M,K] @ Bt[N,K]^T + bias ----------------
// MODE 0: BM=128, 256 thr; A = x staged as RAW FP32 via global_load_lds (granule-
//         swizzled), converted bf16 at fragment-read (cvt_pk); B bf16 gload_lds.
//         Single-buffer 2-barrier (measured-best structure, r11). LDS-bounce
//         epilogue -> qfrag (scaled) / kfrag / vsw, fragment-ordered bf16.
// MODE 1: BM=128, 256 thr, bf16 A gload_lds; f32 out [M][512].
template<int MODE>
__global__ __launch_bounds__(256, 2) void gemm_bt(
    const float* __restrict__ Ax, const u16* __restrict__ A,
    const u16* __restrict__ Bt, const float* __restrict__ bvec,
    u16* __restrict__ oq, u16* __restrict__ ok, u16* __restrict__ ov,
    float* __restrict__ of) {
  constexpr int K = 512;
  constexpr int NBN = (MODE == 0) ? 12 : 4;
  constexpr int PER_XCD = (MODE == 0) ? 384 : 128;
  // MODE0: Af fp32 32KB + Bs 16KB = 48KB.  MODE1: As + Bs bf16 = 32KB.
  __shared__ __align__(16) char SMc[(MODE == 0) ? 49152 : 32768];
  float* Af = (float*)SMc;                                    // MODE0 A (fp32)
  u16* As = (u16*)SMc;                                        // MODE1 A (bf16)
  u16* Bs = (MODE == 0) ? (u16*)(SMc + 32768) : (u16*)(SMc + 16384);
  const int tid = threadIdx.x, lane = tid & 63, w = tid >> 6;
  const int wr = w >> 1, wc = w & 1, lr = lane & 15, lg = lane >> 4;
  // XCD-chunked 1-D grid: bm-pair x all-bn contiguous per XCD (A+B L2-resident)
  const int logical = (blockIdx.x & 7) * PER_XCD + (blockIdx.x >> 3);
  const int bm = (logical / (2 * NBN)) * 2 + (logical & 1);
  const int bn = (logical % (2 * NBN)) >> 1;
  const u16* Bg = Bt + (size_t)bn * 128 * K;
  f32x4 acc[4][4];
#pragma unroll
  for (int m = 0; m < 4; ++m)
#pragma unroll
    for (int n = 0; n < 4; ++n) acc[m][n] = (f32x4){0.f, 0.f, 0.f, 0.f};

  if (MODE == 0) {
    const float* Abase = Ax + (size_t)(bm * 128) * K;
    for (int k0 = 0; k0 < K; k0 += 64) {
      // A: 32KB fp32, granule-swizzled (slot g holds global granule g^(r&7))
#pragma unroll
      for (int it = 0; it < 8; ++it) {
        int chunk = it * 256 + tid;           // (r, g): r = chunk>>4, g = chunk&15
        int r = chunk >> 4, g = chunk & 15;
        int gg = g ^ (r & 7);
        __builtin_amdgcn_global_load_lds(AS1(Abase + (size_t)r * K + k0 + gg * 4),
                                         AS3((char*)Af + chunk * 16), 16, 0, 0);
      }
      // B: 16KB bf16, chunk-swizzled as before
#pragma unroll
      for (int it = 0; it < 4; ++it) {
        int chunk = it * 256 + tid;
        int r = chunk >> 3, kcs = (chunk & 7) ^ (r & 7);
        __builtin_amdgcn_global_load_lds(AS1(Bg + (size_t)r * K + k0 + kcs * 8),
                                         AS3(Bs + chunk * 8), 16, 0, 0);
      }
      __syncthreads();
#pragma unroll
      for (int kk = 0; kk < 2; ++kk) {
        bf16x8 a[4], b[4];
#pragma unroll
        for (int m = 0; m < 4; ++m) {
          int ar = wr * 64 + m * 16 + lr;
          int G = kk * 8 + lg * 2;            // global granule (4 floats each)
          const char* rbase = (const char*)Af + ar * 256;
          float4 f0 = *(const float4*)(rbase + ((G ^ (ar & 7)) << 4));
          float4 f1 = *(const float4*)(rbase + (((G + 1) ^ (ar & 7)) << 4));
          u16 ha[8] = {f2bc(f0.x), f2bc(f0.y), f2bc(f0.z), f2bc(f0.w),
                       f2bc(f1.x), f2bc(f1.y), f2bc(f1.z), f2bc(f1.w)};
          __builtin_memcpy(&a[m], ha, 16);
        }
#pragma unroll
        for (int n = 0; n < 4; ++n) {
          int br = wc * 64 + n * 16 + lr;
          b[n] = *(const bf16x8*)&Bs[br * 64 + (((kk * 4 + lg) ^ (lr & 7)) << 3)];
        }
#pragma unroll
        for (int m = 0; m < 4; ++m)
#pragma unroll
          for (int n = 0; n < 4; ++n)
            acc[m][n] = __builtin_amdgcn_mfma_f32_16x16x32_bf16(a[m], b[n], acc[m][n], 0, 0, 0);
      }
      __syncthreads();
    }
  } else {
    const u16* Ag = A + (size_t)bm * 128 * K;
    for (int k0 = 0; k0 < K; k0 += 64) {
#pragma unroll
      for (int it = 0; it < 4; ++it) {
        int chunk = it * 256 + tid;
        int r = chunk >> 3, kcs = (chunk & 7) ^ (r & 7);
        __builtin_amdgcn_global_load_lds(AS1(Ag + (size_t)r * K + k0 + kcs * 8),
                                         AS3(As + chunk * 8), 16, 0, 0);
        __builtin_amdgcn_global_load_lds(AS1(Bg + (size_t)r * K + k0 + kcs * 8),
                                         AS3(Bs + chunk * 8), 16, 0, 0);
      }
      __syncthreads();
#pragma unroll
      for (int kk = 0; kk < 2; ++kk) {
        bf16x8 a[4], b[4];
#pragma unroll
        for (int m = 0; m < 4; ++m) {
          int ar = wr * 64 + m * 16 + lr;
          a[m] = *(const bf16x8*)&As[ar * 64 + (((kk * 4 + lg) ^ (lr & 7)) << 3)];
        }
#pragma unroll
        for (int n = 0; n < 4; ++n) {
          int br = wc * 64 + n * 16 + lr;
          b[n] = *(const bf16x8*)&Bs[br * 64 + (((kk * 4 + lg) ^ (lr & 7)) << 3)];
        }
#pragma unroll
        for (int m = 0; m < 4; ++m)
#pragma unroll
          for (int n = 0; n < 4; ++n)
            acc[m][n] = __builtin_amdgcn_mfma_f32_16x16x32_bf16(a[m], b[n], acc[m][n], 0, 0, 0);
      }
      __syncthreads();
    }
  }

  if (MODE == 1) {
#pragma unroll
    for (int m = 0; m < 4; ++m)
#pragma unroll
      for (int n = 0; n < 4; ++n)
#pragma unroll
        for (int r = 0; r < 4; ++r) {
          int row = bm * 128 + wr * 64 + m * 16 + lg * 4 + r;
          int col = bn * 128 + wc * 64 + n * 16 + lr;
          of[(size_t)row * CDIM + col] = acc[m][n][r] + bvec[col];
        }
    return;
  }

  // ---- MODE 0 epilogue: bounce via per-wave swizzled 64x64 bf16 LDS tile ----
  const int typ = bn >> 2;                 // 0=Q, 1=K, 2=V
  const int col0 = bn * 128 + wc * 64;
  const int row0 = bm * 128 + wr * 64;
  char* Tb = SMc + w * 8192;               // 8 KB per wave (staging dead)

#pragma unroll
  for (int n = 0; n < 4; ++n) {
    float bv = bvec[col0 + n * 16 + lr];
#pragma unroll
    for (int m = 0; m < 4; ++m)
#pragma unroll
      for (int r = 0; r < 4; ++r) {
        float v = acc[m][n][r] + bv;
        if (typ == 0) v *= QSCALE;
        int row_l, col_l;
        if (typ < 2) { row_l = m * 16 + lg * 4 + r; col_l = n * 16 + lr; }
        else         { row_l = n * 16 + lr;         col_l = m * 16 + lg * 4 + r; }  // V: transposed
        int byte = row_l * 128 + ((((col_l >> 3) ^ (row_l & 7)) << 4) | ((col_l & 7) << 1));
        *(u16*)(Tb + byte) = f2b(v);
      }
  }
  asm volatile("" ::: "memory");   // pin LDS write->read order (strict-aliasing guard)
  if (typ < 2) {
    int tok = row0 + lane;
    int tokb = tok >> 8;
    u16* obase = (typ == 0) ? oq : ok;
#pragma unroll
    for (int G = 0; G < 8; ++G) {
      int hl = G >> 2, q = G & 3;
      uint4 v = *(const uint4*)(Tb + lane * 128 + ((G ^ (lane & 7)) << 4));
      int hh = ((col0 >> 5) & 15) + hl;     // head index
      size_t a = ((((size_t)tokb * 16 + hh) * 16 + ((tok >> 4) & 15)) * 64 +
                  ((tok & 15) | (q << 4))) * 8;
      *(uint4*)(obase + a) = v;
    }
  } else {
    int tl0 = row0 & 255, tokb = row0 >> 8;
    int hl = lane >> 5, t = (lane >> 3) & 3, c = lane & 7;
    int hh = ((col0 >> 5) & 15) + hl;       // head index
#pragma unroll
    for (int i = 0; i < 8; ++i) {
      int d = i * 4 + t;
      uint4 v = *(const uint4*)(Tb + (hl * 32 + d) * 128 + (c << 4));
      size_t a = (((size_t)tokb * 16 + hh) * 32 + d) * 256 + tl0 + c * 8;
      *(uint4*)(ov + a) = v;
    }
  }
}

// ---------------- fused attention: 512-thread block = (b, h, qpair), 8 waves ----------------
__global__ __launch_bounds__(512, 4) void attn_kernel(const u16* __restrict__ qfrag,
                                                      const u16* __restrict__ kfrag,
                                                      const u16* __restrict__ vsw,
                                                      const u16* __restrict__ bias2,
                                                      const u16* __restrict__ mod2,
                                                      u16* __restrict__ attnout) {
  __shared__ __align__(16) u16 SM[24576];
  const int logical = (blockIdx.x & 7) * 512 + (blockIdx.x >> 3);   // 4096 blocks
  const int h = logical >> 8;           // 2 heads per XCD (bias/mod L2-resident)
  const int b = (logical >> 1) & 127;   // qpair-adjacent -> K/V L2 reuse
  const int qpair = logical & 1;
  const int tid = threadIdx.x, lane = tid & 63, w = tid >> 6;
  const int lr = lane & 15, lg = lane >> 4;
  const int rb = qpair * 8 + w;         // this wave's row-block (16 q rows)
  const int bhid = b * 16 + h;

  const u16* kg = kfrag + (size_t)bhid * 8192;
  const u16* vg = vsw + (size_t)bhid * 8192;
#pragma unroll
  for (int it = 0; it < 2; ++it) {
    __builtin_amdgcn_global_load_lds(AS1(kg + (it * 512 + tid) * 8),
                                     AS3(SM + (it * 512 + tid) * 8), 16, 0, 0);
    __builtin_amdgcn_global_load_lds(AS1(vg + (it * 512 + tid) * 8),
                                     AS3(SM + 8192 + (it * 512 + tid) * 8), 16, 0, 0);
  }
  bf16x8 qf = *(const bf16x8*)(qfrag + ((size_t)bhid * 16 + rb) * 512 + lane * 8);
  __syncthreads();

  const u16* bias_base = bias2 + (((size_t)h * 16 + rb) * 64 + lane) * 64;
  const u16* mod_base  = mod2 + ((size_t)rb * 64 + lane) * 64;
  char* Pbase = (char*)SM + 32768 + w * 2048;
  const char* Vb = (const char*)(SM + 8192);

  // S^T = K Q^T + bias : full 16 tiles, per-quarter transient bias loads
  f32x4 s[16];
#pragma unroll
  for (int q = 0; q < 4; ++q) {
    u32 bw8[8];
    {
      const uint4* bp = (const uint4*)(bias_base + q * 16);
      *(uint4*)&bw8[0] = bp[0]; *(uint4*)&bw8[4] = bp[1];
    }
#pragma unroll
    for (int tl = 0; tl < 4; ++tl) {
      int t = q * 4 + tl;
      bf16x8 kf = *(const bf16x8*)(SM + (t * 64 + lane) * 8);
      f32x4 c;
      c[0] = bf_lo(bw8[tl * 2]);     c[1] = bf_hi(bw8[tl * 2]);
      c[2] = bf_lo(bw8[tl * 2 + 1]); c[3] = bf_hi(bw8[tl * 2 + 1]);
      s[t] = __builtin_amdgcn_mfma_f32_16x16x32_bf16(kf, qf, c, 0, 0, 0);
    }
  }

  // softmax over m (log2 domain): 4 parallel max chains + 2 shuffles
  float mr0 = s[0][0], mr1 = s[0][1], mr2 = s[0][2], mr3 = s[0][3];
#pragma unroll
  for (int t = 1; t < 16; ++t) {
    mr0 = fmaxf(mr0, s[t][0]); mr1 = fmaxf(mr1, s[t][1]);
    mr2 = fmaxf(mr2, s[t][2]); mr3 = fmaxf(mr3, s[t][3]);
  }
  float mx = fmaxf(fmaxf(mr0, mr1), fmaxf(mr2, mr3));
  mx = fmaxf(mx, __shfl_xor(mx, 16, 64));
  mx = fmaxf(mx, __shfl_xor(mx, 32, 64));
  float s0 = 0.f, s1 = 0.f, s2 = 0.f, s3 = 0.f;
#pragma unroll
  for (int t = 0; t < 16; ++t) {
    s[t][0] = ex2(s[t][0] - mx); s0 += s[t][0];
    s[t][1] = ex2(s[t][1] - mx); s1 += s[t][1];
    s[t][2] = ex2(s[t][2] - mx); s2 += s[t][2];
    s[t][3] = ex2(s[t][3] - mx); s3 += s[t][3];
  }
  float sm = (s0 + s1) + (s2 + s3);
  sm += __shfl_xor(sm, 16, 64);
  sm += __shfl_xor(sm, 32, 64);
  sm = __builtin_amdgcn_rcpf(sm);   // own-lane: denominator for query n = lr (pre-pack norm)

  // quarter-partitioned pack (normalized P, mod applied) + PV
  f32x4 o0 = (f32x4){0.f, 0.f, 0.f, 0.f};
  f32x4 o1 = (f32x4){0.f, 0.f, 0.f, 0.f};
#pragma unroll
  for (int q = 0; q < 4; ++q) {
    u32 mw8[8];
    {
      const uint4* mp = (const uint4*)(mod_base + q * 16);
      *(uint4*)&mw8[0] = mp[0]; *(uint4*)&mw8[4] = mp[1];
    }
#pragma unroll
    for (int tl = 0; tl < 4; ++tl) {
      int t = q * 4 + tl;
      u16 pk[4];
#pragma unroll
      for (int r = 0; r < 4; ++r) {
        u32 wd = mw8[tl * 2 + (r >> 1)];
        float mf = (r & 1) ? bf_hi(wd) : bf_lo(wd);
        pk[r] = f2bc(s[t][r] * sm * mf);
      }
      int hi2 = (t * 2 + (lg >> 1)) & 3;
      *(uint2*)(Pbase + ((t >> 1) & 1) * 1024 + ((hi2 << 4) | lr) * 16 + (lg & 1) * 8)
          = *(const uint2*)pk;
    }
    asm volatile("" ::: "memory");   // pack stores must precede PV loads
#pragma unroll
    for (int kl = 0; kl < 2; ++kl) {
      bf16x8 pa = *(const bf16x8*)(Pbase + kl * 1024 + lane * 16);
      int cv = ((q * 2 + kl) * 4 + lg) ^ (lr & 7);
      bf16x8 v0 = *(const bf16x8*)(Vb + lr * 512 + cv * 16);
      bf16x8 v1 = *(const bf16x8*)(Vb + (16 + lr) * 512 + cv * 16);
      o0 = __builtin_amdgcn_mfma_f32_16x16x32_bf16(pa, v0, o0, 0, 0, 0);
      o1 = __builtin_amdgcn_mfma_f32_16x16x32_bf16(pa, v1, o1, 0, 0, 0);
    }
    asm volatile("" ::: "memory");   // PV loads must precede next quarter's pack (WAR)
  }

  u16* orow = attnout + (size_t)(b * TOK + rb * 16) * CDIM + h * 32;
#pragma unroll
  for (int r = 0; r < 4; ++r) {
    orow[(size_t)(lg * 4 + r) * CDIM + lr] = f2bc(o0[r]);
    orow[(size_t)(lg * 4 + r) * CDIM + 16 + lr] = f2bc(o1[r]);
  }
}

// ---------------- launch ----------------
extern "C" void kernel_launch(void* const* d_in, const int* in_sizes, int n_in,
                              void* d_out, int out_size, void* d_ws, size_t ws_size,
                              hipStream_t stream) {
  const float* x      = (const float*)d_in[0];
  const float* qkv_w  = (const float*)d_in[1];
  const float* qkv_b  = (const float*)d_in[2];
  const float* proj_w = (const float*)d_in[3];
  const float* proj_b = (const float*)d_in[4];
  const float* rpb    = (const float*)d_in[5];

  char* ws = (char*)d_ws;
  u16* qkvwb  = (u16*)(ws + 33554432);      //  1,572,864 B
  u16* projwb = (u16*)(ws + 35127296);      //    524,288 B
  u16* qfrag  = (u16*)(ws + 35651584);      // 33,554,432 B
  u16* kfrag  = (u16*)(ws + 69206016);      // 33,554,432 B
  u16* vswb   = (u16*)(ws + 102760448);     // 33,554,432 B
  u16* attnb  = (u16*)(ws + 136314880);     // 33,554,432 B
  u16* bias2  = (u16*)(ws + 169869312);     //  2,097,152 B
  u16* mod2   = (u16*)(ws + 171966464);     //    131,072 B

  cvt_bf16_kernel<<<384, 256, 0, stream>>>(qkv_w, qkvwb, 1536 * 512);
  cvt_bf16_kernel<<<128, 256, 0, stream>>>(proj_w, projwb, 512 * 512);
  build_bias2_kernel<<<4096, 256, 0, stream>>>(rpb, bias2);
  build_mod2_kernel<<<256, 256, 0, stream>>>(mod2);

  gemm_bt<0><<<3072, 256, 0, stream>>>(x, nullptr, qkvwb, qkv_b,
                                       qfrag, kfrag, vswb, nullptr);
  attn_kernel<<<4096, 512, 0, stream>>>(qfrag, kfrag, vswb, bias2, mod2, attnb);
  gemm_bt<1><<<1024, 256, 0, stream>>>(nullptr, attnb, projwb, proj_b,
                                       nullptr, nullptr, nullptr, (float*)d_out);
}

// Round 16
// 224.485 us; speedup vs baseline: 1.0699x; 1.0093x over previous
//
#include <hip/hip_runtime.h>
#include <hip/hip_bf16.h>

typedef unsigned short u16;
typedef unsigned int u32;
typedef __bf16 bf16x8 __attribute__((ext_vector_type(8)));
typedef float f32x4 __attribute__((ext_vector_type(4)));

#define AS1(p) ((const __attribute__((address_space(1))) void*)(p))
#define AS3(p) ((__attribute__((address_space(3))) void*)(p))

#define TOK   256
#define CDIM  512
#define QKVC  1536
#define LOG2E 1.4426950408889634f
#define QSCALE (0.17677669529663687f * 1.4426950408889634f)  // D^-0.5 * log2e

__device__ __forceinline__ u16 f2b(float f) {
  unsigned u = __float_as_uint(f);
  unsigned r = (u + 0x7fffu + ((u >> 16) & 1u)) >> 16;
  return (u16)r;
}
__device__ __forceinline__ u16 f2bc(float f) {
  __bf16 h = (__bf16)f;
  u16 u;
  __builtin_memcpy(&u, &h, 2);
  return u;
}
__device__ __forceinline__ float bf_lo(u32 wd) { return __uint_as_float(wd << 16); }
__device__ __forceinline__ float bf_hi(u32 wd) { return __uint_as_float(wd & 0xffff0000u); }
__device__ __forceinline__ float ex2(float x) {
  float r;
  asm("v_exp_f32 %0, %1" : "=v"(r) : "v"(x));
  return r;
}

// ---------------- fp32 -> bf16 conversion (weights only) ----------------
__global__ __launch_bounds__(256) void cvt_bf16_kernel(const float* __restrict__ in,
                                                       u16* __restrict__ out, int n) {
  int i = (blockIdx.x * 256 + threadIdx.x) * 8;
  if (i >= n) return;
  float4 a = *(const float4*)(in + i);
  float4 b = *(const float4*)(in + i + 4);
  u16 h[8];
  h[0] = f2b(a.x); h[1] = f2b(a.y); h[2] = f2b(a.z); h[3] = f2b(a.w);
  h[4] = f2b(b.x); h[5] = f2b(b.y); h[6] = f2b(b.z); h[7] = f2b(b.w);
  *(uint4*)(out + i) = *(const uint4*)h;
}

// ---------------- bias2: S^T fragment layout, bf16, pre-multiplied by log2e ----------------
__global__ __launch_bounds__(256) void build_bias2_kernel(const float* __restrict__ rpb,
                                                          u16* __restrict__ bias2) {
  int i = blockIdx.x * 256 + threadIdx.x;   // 16*16*64*64 = 2^20
  int tr = i & 63, lane = (i >> 6) & 63, rb = (i >> 12) & 15, h = i >> 16;
  int t = tr >> 2, r = tr & 3;
  int n = rb * 16 + (lane & 15);
  int m = t * 16 + (lane >> 4) * 4 + r;
  int idx = ((n >> 4) - (m >> 4) + 15) * 31 + ((n & 15) - (m & 15) + 15);
  bias2[i] = f2b(rpb[idx * 16 + h] * LOG2E);
}

// ---------------- mod2: S^T fragment layout, bf16 ----------------
__global__ __launch_bounds__(256) void build_mod2_kernel(u16* __restrict__ mod2) {
  int i = blockIdx.x * 256 + threadIdx.x;   // 16*64*64 = 65536
  int tr = i & 63, lane = (i >> 6) & 63, rb = i >> 12;
  int t = tr >> 2, r = tr & 3;
  int n = rb * 16 + (lane & 15);
  int m = t * 16 + (lane >> 4) * 4 + r;
  int dr = (n >> 4) - (m >> 4), dc = (n & 15) - (m & 15);
  int d2 = dr * dr + dc * dc;
  float val = 0.0f;
  if (d2 <= 229) {   // exact integer form of (m >= bound); boundary at d2==229
    const float fc = 6.2831853071795864f / (60.0f * 1.4142135623730951f);
    val = expf(cosf(fc * sqrtf((float)d2))) * 0.5f;
  }
  mod2[i] = f2b(val);
}

// ---------------- bf16 GEMM: out = A[M,K] @ Bt[N,K]^T + bias ----------------
// MODE 0: BM=128, 256 thr, 32KB LDS; A = x fp32 reg-staged + cvt'd in staging
//         (loads issued first, then B gload_lds, then cvt+ds_write -> all loads in
//         flight before the vmcnt stall). Single-buffer 2-barrier (measured-best
//         geometry, r11). LDS-bounce epilogue -> qfrag (scaled) / kfrag / vsw.
// MODE 1: BM=128, 256 thr, bf16 A gload_lds; f32 out [M][512].
template<int MODE>
__global__ __launch_bounds__(256, 2) void gemm_bt(
    const float* __restrict__ Ax, const u16* __restrict__ A,
    const u16* __restrict__ Bt, const float* __restrict__ bvec,
    u16* __restrict__ oq, u16* __restrict__ ok, u16* __restrict__ ov,
    float* __restrict__ of) {
  constexpr int K = 512;
  constexpr int NBN = (MODE == 0) ? 12 : 4;
  constexpr int PER_XCD = (MODE == 0) ? 384 : 128;
  __shared__ __align__(16) u16 SM[16384];   // 32KB: As 16KB + Bs 16KB
  u16* As = SM;
  u16* Bs = SM + 8192;
  const int tid = threadIdx.x, lane = tid & 63, w = tid >> 6;
  const int wr = w >> 1, wc = w & 1, lr = lane & 15, lg = lane >> 4;
  // XCD-chunked 1-D grid: bm-pair x all-bn contiguous per XCD (A+B L2-resident)
  const int logical = (blockIdx.x & 7) * PER_XCD + (blockIdx.x >> 3);
  const int bm = (logical / (2 * NBN)) * 2 + (logical & 1);
  const int bn = (logical % (2 * NBN)) >> 1;
  const u16* Bg = Bt + (size_t)bn * 128 * K;
  f32x4 acc[4][4];
#pragma unroll
  for (int m = 0; m < 4; ++m)
#pragma unroll
    for (int n = 0; n < 4; ++n) acc[m][n] = (f32x4){0.f, 0.f, 0.f, 0.f};

  if (MODE == 0) {
    const float* Abase = Ax + (size_t)(bm * 128) * K;
    for (int k0 = 0; k0 < K; k0 += 64) {
      // A: fp32 -> regs (issued first; 2 x dwordx4 per chunk)
      float4 pa0[4], pa1[4];
#pragma unroll
      for (int it = 0; it < 4; ++it) {
        int chunk = it * 256 + tid;           // (r, kc): r = chunk>>3, kc = chunk&7
        int r = chunk >> 3, gg = (chunk & 7) ^ (r & 7);
        const float* src = Abase + (size_t)r * K + k0 + gg * 8;
        pa0[it] = *(const float4*)src;
        pa1[it] = *(const float4*)(src + 4);
      }
      // B: gload_lds with pre-swizzled source granule (in flight during A wait)
#pragma unroll
      for (int it = 0; it < 4; ++it) {
        int chunk = it * 256 + tid;
        int r = chunk >> 3, kcs = (chunk & 7) ^ (r & 7);
        __builtin_amdgcn_global_load_lds(AS1(Bg + (size_t)r * K + k0 + kcs * 8),
                                         AS3(Bs + chunk * 8), 16, 0, 0);
      }
      // A: cvt + swizzled ds_write (slot kc holds global granule kc^(r&7))
#pragma unroll
      for (int it = 0; it < 4; ++it) {
        int chunk = it * 256 + tid;
        u16 hb[8];
        hb[0] = f2bc(pa0[it].x); hb[1] = f2bc(pa0[it].y);
        hb[2] = f2bc(pa0[it].z); hb[3] = f2bc(pa0[it].w);
        hb[4] = f2bc(pa1[it].x); hb[5] = f2bc(pa1[it].y);
        hb[6] = f2bc(pa1[it].z); hb[7] = f2bc(pa1[it].w);
        *(uint4*)(As + chunk * 8) = *(const uint4*)hb;
      }
      __syncthreads();
#pragma unroll
      for (int kk = 0; kk < 2; ++kk) {
        bf16x8 a[4], b[4];
#pragma unroll
        for (int m = 0; m < 4; ++m) {
          int ar = wr * 64 + m * 16 + lr;
          a[m] = *(const bf16x8*)&As[ar * 64 + (((kk * 4 + lg) ^ (lr & 7)) << 3)];
        }
#pragma unroll
        for (int n = 0; n < 4; ++n) {
          int br = wc * 64 + n * 16 + lr;
          b[n] = *(const bf16x8*)&Bs[br * 64 + (((kk * 4 + lg) ^ (lr & 7)) << 3)];
        }
#pragma unroll
        for (int m = 0; m < 4; ++m)
#pragma unroll
          for (int n = 0; n < 4; ++n)
            acc[m][n] = __builtin_amdgcn_mfma_f32_16x16x32_bf16(a[m], b[n], acc[m][n], 0, 0, 0);
      }
      __syncthreads();
    }
  } else {
    const u16* Ag = A + (size_t)bm * 128 * K;
    for (int k0 = 0; k0 < K; k0 += 64) {
#pragma unroll
      for (int it = 0; it < 4; ++it) {
        int chunk = it * 256 + tid;
        int r = chunk >> 3, kcs = (chunk & 7) ^ (r & 7);
        __builtin_amdgcn_global_load_lds(AS1(Ag + (size_t)r * K + k0 + kcs * 8),
                                         AS3(As + chunk * 8), 16, 0, 0);
        __builtin_amdgcn_global_load_lds(AS1(Bg + (size_t)r * K + k0 + kcs * 8),
                                         AS3(Bs + chunk * 8), 16, 0, 0);
      }
      __syncthreads();
#pragma unroll
      for (int kk = 0; kk < 2; ++kk) {
        bf16x8 a[4], b[4];
#pragma unroll
        for (int m = 0; m < 4; ++m) {
          int ar = wr * 64 + m * 16 + lr;
          a[m] = *(const bf16x8*)&As[ar * 64 + (((kk * 4 + lg) ^ (lr & 7)) << 3)];
        }
#pragma unroll
        for (int n = 0; n < 4; ++n) {
          int br = wc * 64 + n * 16 + lr;
          b[n] = *(const bf16x8*)&Bs[br * 64 + (((kk * 4 + lg) ^ (lr & 7)) << 3)];
        }
#pragma unroll
        for (int m = 0; m < 4; ++m)
#pragma unroll
          for (int n = 0; n < 4; ++n)
            acc[m][n] = __builtin_amdgcn_mfma_f32_16x16x32_bf16(a[m], b[n], acc[m][n], 0, 0, 0);
      }
      __syncthreads();
    }
  }

  if (MODE == 1) {
#pragma unroll
    for (int m = 0; m < 4; ++m)
#pragma unroll
      for (int n = 0; n < 4; ++n)
#pragma unroll
        for (int r = 0; r < 4; ++r) {
          int row = bm * 128 + wr * 64 + m * 16 + lg * 4 + r;
          int col = bn * 128 + wc * 64 + n * 16 + lr;
          of[(size_t)row * CDIM + col] = acc[m][n][r] + bvec[col];
        }
    return;
  }

  // ---- MODE 0 epilogue: bounce via per-wave swizzled 64x64 bf16 LDS tile ----
  const int typ = bn >> 2;                 // 0=Q, 1=K, 2=V
  const int col0 = bn * 128 + wc * 64;
  const int row0 = bm * 128 + wr * 64;
  char* Tb = (char*)SM + w * 8192;         // 8 KB per wave (staging dead)

#pragma unroll
  for (int n = 0; n < 4; ++n) {
    float bv = bvec[col0 + n * 16 + lr];
#pragma unroll
    for (int m = 0; m < 4; ++m)
#pragma unroll
      for (int r = 0; r < 4; ++r) {
        float v = acc[m][n][r] + bv;
        if (typ == 0) v *= QSCALE;
        int row_l, col_l;
        if (typ < 2) { row_l = m * 16 + lg * 4 + r; col_l = n * 16 + lr; }
        else         { row_l = n * 16 + lr;         col_l = m * 16 + lg * 4 + r; }  // V: transposed
        int byte = row_l * 128 + ((((col_l >> 3) ^ (row_l & 7)) << 4) | ((col_l & 7) << 1));
        *(u16*)(Tb + byte) = f2b(v);
      }
  }
  asm volatile("" ::: "memory");   // pin LDS write->read order (strict-aliasing guard)
  if (typ < 2) {
    int tok = row0 + lane;
    int tokb = tok >> 8;
    u16* obase = (typ == 0) ? oq : ok;
#pragma unroll
    for (int G = 0; G < 8; ++G) {
      int hl = G >> 2, q = G & 3;
      uint4 v = *(const uint4*)(Tb + lane * 128 + ((G ^ (lane & 7)) << 4));
      int hh = ((col0 >> 5) & 15) + hl;     // head index
      size_t a = ((((size_t)tokb * 16 + hh) * 16 + ((tok >> 4) & 15)) * 64 +
                  ((tok & 15) | (q << 4))) * 8;
      *(uint4*)(obase + a) = v;
    }
  } else {
    int tl0 = row0 & 255, tokb = row0 >> 8;
    int hl = lane >> 5, t = (lane >> 3) & 3, c = lane & 7;
    int hh = ((col0 >> 5) & 15) + hl;       // head index
#pragma unroll
    for (int i = 0; i < 8; ++i) {
      int d = i * 4 + t;
      uint4 v = *(const uint4*)(Tb + (hl * 32 + d) * 128 + (c << 4));
      size_t a = (((size_t)tokb * 16 + hh) * 32 + d) * 256 + tl0 + c * 8;
      *(uint4*)(ov + a) = v;
    }
  }
}

// ---------------- fused attention: 512-thread block = (b, h, qpair), 8 waves ----------------
__global__ __launch_bounds__(512, 4) void attn_kernel(const u16* __restrict__ qfrag,
                                                      const u16* __restrict__ kfrag,
                                                      const u16* __restrict__ vsw,
                                                      const u16* __restrict__ bias2,
                                                      const u16* __restrict__ mod2,
                                                      u16* __restrict__ attnout) {
  __shared__ __align__(16) u16 SM[24576];
  const int logical = (blockIdx.x & 7) * 512 + (blockIdx.x >> 3);   // 4096 blocks
  const int h = logical >> 8;           // 2 heads per XCD (bias/mod L2-resident)
  const int b = (logical >> 1) & 127;   // qpair-adjacent -> K/V L2 reuse
  const int qpair = logical & 1;
  const int tid = threadIdx.x, lane = tid & 63, w = tid >> 6;
  const int lr = lane & 15, lg = lane >> 4;
  const int rb = qpair * 8 + w;         // this wave's row-block (16 q rows)
  const int bhid = b * 16 + h;

  const u16* kg = kfrag + (size_t)bhid * 8192;
  const u16* vg = vsw + (size_t)bhid * 8192;
#pragma unroll
  for (int it = 0; it < 2; ++it) {
    __builtin_amdgcn_global_load_lds(AS1(kg + (it * 512 + tid) * 8),
                                     AS3(SM + (it * 512 + tid) * 8), 16, 0, 0);
    __builtin_amdgcn_global_load_lds(AS1(vg + (it * 512 + tid) * 8),
                                     AS3(SM + 8192 + (it * 512 + tid) * 8), 16, 0, 0);
  }
  bf16x8 qf = *(const bf16x8*)(qfrag + ((size_t)bhid * 16 + rb) * 512 + lane * 8);
  __syncthreads();

  const u16* bias_base = bias2 + (((size_t)h * 16 + rb) * 64 + lane) * 64;
  const u16* mod_base  = mod2 + ((size_t)rb * 64 + lane) * 64;
  char* Pbase = (char*)SM + 32768 + w * 2048;
  const char* Vb = (const char*)(SM + 8192);

  // S^T = K Q^T + bias : full 16 tiles, per-quarter transient bias loads
  f32x4 s[16];
#pragma unroll
  for (int q = 0; q < 4; ++q) {
    u32 bw8[8];
    {
      const uint4* bp = (const uint4*)(bias_base + q * 16);
      *(uint4*)&bw8[0] = bp[0]; *(uint4*)&bw8[4] = bp[1];
    }
#pragma unroll
    for (int tl = 0; tl < 4; ++tl) {
      int t = q * 4 + tl;
      bf16x8 kf = *(const bf16x8*)(SM + (t * 64 + lane) * 8);
      f32x4 c;
      c[0] = bf_lo(bw8[tl * 2]);     c[1] = bf_hi(bw8[tl * 2]);
      c[2] = bf_lo(bw8[tl * 2 + 1]); c[3] = bf_hi(bw8[tl * 2 + 1]);
      s[t] = __builtin_amdgcn_mfma_f32_16x16x32_bf16(kf, qf, c, 0, 0, 0);
    }
  }

  // softmax over m (log2 domain): 4 parallel max chains + 2 shuffles
  float mr0 = s[0][0], mr1 = s[0][1], mr2 = s[0][2], mr3 = s[0][3];
#pragma unroll
  for (int t = 1; t < 16; ++t) {
    mr0 = fmaxf(mr0, s[t][0]); mr1 = fmaxf(mr1, s[t][1]);
    mr2 = fmaxf(mr2, s[t][2]); mr3 = fmaxf(mr3, s[t][3]);
  }
  float mx = fmaxf(fmaxf(mr0, mr1), fmaxf(mr2, mr3));
  mx = fmaxf(mx, __shfl_xor(mx, 16, 64));
  mx = fmaxf(mx, __shfl_xor(mx, 32, 64));
  float s0 = 0.f, s1 = 0.f, s2 = 0.f, s3 = 0.f;
#pragma unroll
  for (int t = 0; t < 16; ++t) {
    s[t][0] = ex2(s[t][0] - mx); s0 += s[t][0];
    s[t][1] = ex2(s[t][1] - mx); s1 += s[t][1];
    s[t][2] = ex2(s[t][2] - mx); s2 += s[t][2];
    s[t][3] = ex2(s[t][3] - mx); s3 += s[t][3];
  }
  float sm = (s0 + s1) + (s2 + s3);
  sm += __shfl_xor(sm, 16, 64);
  sm += __shfl_xor(sm, 32, 64);
  sm = __builtin_amdgcn_rcpf(sm);   // own-lane: denominator for query n = lr (pre-pack norm)

  // quarter-partitioned pack (normalized P, mod applied) + PV
  f32x4 o0 = (f32x4){0.f, 0.f, 0.f, 0.f};
  f32x4 o1 = (f32x4){0.f, 0.f, 0.f, 0.f};
#pragma unroll
  for (int q = 0; q < 4; ++q) {
    u32 mw8[8];
    {
      const uint4* mp = (const uint4*)(mod_base + q * 16);
      *(uint4*)&mw8[0] = mp[0]; *(uint4*)&mw8[4] = mp[1];
    }
#pragma unroll
    for (int tl = 0; tl < 4; ++tl) {
      int t = q * 4 + tl;
      u16 pk[4];
#pragma unroll
      for (int r = 0; r < 4; ++r) {
        u32 wd = mw8[tl * 2 + (r >> 1)];
        float mf = (r & 1) ? bf_hi(wd) : bf_lo(wd);
        pk[r] = f2bc(s[t][r] * sm * mf);
      }
      int hi2 = (t * 2 + (lg >> 1)) & 3;
      *(uint2*)(Pbase + ((t >> 1) & 1) * 1024 + ((hi2 << 4) | lr) * 16 + (lg & 1) * 8)
          = *(const uint2*)pk;
    }
    asm volatile("" ::: "memory");   // pack stores must precede PV loads
#pragma unroll
    for (int kl = 0; kl < 2; ++kl) {
      bf16x8 pa = *(const bf16x8*)(Pbase + kl * 1024 + lane * 16);
      int cv = ((q * 2 + kl) * 4 + lg) ^ (lr & 7);
      bf16x8 v0 = *(const bf16x8*)(Vb + lr * 512 + cv * 16);
      bf16x8 v1 = *(const bf16x8*)(Vb + (16 + lr) * 512 + cv * 16);
      o0 = __builtin_amdgcn_mfma_f32_16x16x32_bf16(pa, v0, o0, 0, 0, 0);
      o1 = __builtin_amdgcn_mfma_f32_16x16x32_bf16(pa, v1, o1, 0, 0, 0);
    }
    asm volatile("" ::: "memory");   // PV loads must precede next quarter's pack (WAR)
  }

  u16* orow = attnout + (size_t)(b * TOK + rb * 16) * CDIM + h * 32;
#pragma unroll
  for (int r = 0; r < 4; ++r) {
    orow[(size_t)(lg * 4 + r) * CDIM + lr] = f2bc(o0[r]);
    orow[(size_t)(lg * 4 + r) * CDIM + 16 + lr] = f2bc(o1[r]);
  }
}

// ---------------- launch ----------------
extern "C" void kernel_launch(void* const* d_in, const int* in_sizes, int n_in,
                              void* d_out, int out_size, void* d_ws, size_t ws_size,
                              hipStream_t stream) {
  const float* x      = (const float*)d_in[0];
  const float* qkv_w  = (const float*)d_in[1];
  const float* qkv_b  = (const float*)d_in[2];
  const float* proj_w = (const float*)d_in[3];
  const float* proj_b = (const float*)d_in[4];
  const float* rpb    = (const float*)d_in[5];

  char* ws = (char*)d_ws;
  u16* qkvwb  = (u16*)(ws + 33554432);      //  1,572,864 B
  u16* projwb = (u16*)(ws + 35127296);      //    524,288 B
  u16* qfrag  = (u16*)(ws + 35651584);      // 33,554,432 B
  u16* kfrag  = (u16*)(ws + 69206016);      // 33,554,432 B
  u16* vswb   = (u16*)(ws + 102760448);     // 33,554,432 B
  u16* attnb  = (u16*)(ws + 136314880);     // 33,554,432 B
  u16* bias2  = (u16*)(ws + 169869312);     //  2,097,152 B
  u16* mod2   = (u16*)(ws + 171966464);     //    131,072 B

  cvt_bf16_kernel<<<384, 256, 0, stream>>>(qkv_w, qkvwb, 1536 * 512);
  cvt_bf16_kernel<<<128, 256, 0, stream>>>(proj_w, projwb, 512 * 512);
  build_bias2_kernel<<<4096, 256, 0, stream>>>(rpb, bias2);
  build_mod2_kernel<<<256, 256, 0, stream>>>(mod2);

  gemm_bt<0><<<3072, 256, 0, stream>>>(x, nullptr, qkvwb, qkv_b,
                                       qfrag, kfrag, vswb, nullptr);
  attn_kernel<<<4096, 512, 0, stream>>>(qfrag, kfrag, vswb, bias2, mod2, attnb);
  gemm_bt<1><<<1024, 256, 0, stream>>>(nullptr, attnb, projwb, proj_b,
                                       nullptr, nullptr, nullptr, (float*)d_out);
}

// Round 17
// 217.487 us; speedup vs baseline: 1.1043x; 1.0322x over previous
//
#include <hip/hip_runtime.h>
#include <hip/hip_bf16.h>

typedef unsigned short u16;
typedef unsigned int u32;
typedef __bf16 bf16x8 __attribute__((ext_vector_type(8)));
typedef float f32x4 __attribute__((ext_vector_type(4)));

#define AS1(p) ((const __attribute__((address_space(1))) void*)(p))
#define AS3(p) ((__attribute__((address_space(3))) void*)(p))

#define TOK   256
#define CDIM  512
#define QKVC  1536
#define LOG2E 1.4426950408889634f
#define QSCALE (0.17677669529663687f * 1.4426950408889634f)  // D^-0.5 * log2e

__device__ __forceinline__ u16 f2b(float f) {
  unsigned u = __float_as_uint(f);
  unsigned r = (u + 0x7fffu + ((u >> 16) & 1u)) >> 16;
  return (u16)r;
}
__device__ __forceinline__ u16 f2bc(float f) {
  __bf16 h = (__bf16)f;
  u16 u;
  __builtin_memcpy(&u, &h, 2);
  return u;
}
__device__ __forceinline__ float bf_lo(u32 wd) { return __uint_as_float(wd << 16); }
__device__ __forceinline__ float bf_hi(u32 wd) { return __uint_as_float(wd & 0xffff0000u); }
__device__ __forceinline__ float ex2(float x) {
  float r;
  asm("v_exp_f32 %0, %1" : "=v"(r) : "v"(x));
  return r;
}

// ---------------- fp32 -> bf16 conversion (weights only) ----------------
__global__ __launch_bounds__(256) void cvt_bf16_kernel(const float* __restrict__ in,
                                                       u16* __restrict__ out, int n) {
  int i = (blockIdx.x * 256 + threadIdx.x) * 8;
  if (i >= n) return;
  float4 a = *(const float4*)(in + i);
  float4 b = *(const float4*)(in + i + 4);
  u16 h[8];
  h[0] = f2b(a.x); h[1] = f2b(a.y); h[2] = f2b(a.z); h[3] = f2b(a.w);
  h[4] = f2b(b.x); h[5] = f2b(b.y); h[6] = f2b(b.z); h[7] = f2b(b.w);
  *(uint4*)(out + i) = *(const uint4*)h;
}

// ---------------- bias2: S^T fragment layout, bf16, pre-multiplied by log2e ----------------
__global__ __launch_bounds__(256) void build_bias2_kernel(const float* __restrict__ rpb,
                                                          u16* __restrict__ bias2) {
  int i = blockIdx.x * 256 + threadIdx.x;   // 16*16*64*64 = 2^20
  int tr = i & 63, lane = (i >> 6) & 63, rb = (i >> 12) & 15, h = i >> 16;
  int t = tr >> 2, r = tr & 3;
  int n = rb * 16 + (lane & 15);
  int m = t * 16 + (lane >> 4) * 4 + r;
  int idx = ((n >> 4) - (m >> 4) + 15) * 31 + ((n & 15) - (m & 15) + 15);
  bias2[i] = f2b(rpb[idx * 16 + h] * LOG2E);
}

// ---------------- mod2: S^T fragment layout, bf16 ----------------
__global__ __launch_bounds__(256) void build_mod2_kernel(u16* __restrict__ mod2) {
  int i = blockIdx.x * 256 + threadIdx.x;   // 16*64*64 = 65536
  int tr = i & 63, lane = (i >> 6) & 63, rb = i >> 12;
  int t = tr >> 2, r = tr & 3;
  int n = rb * 16 + (lane & 15);
  int m = t * 16 + (lane >> 4) * 4 + r;
  int dr = (n >> 4) - (m >> 4), dc = (n & 15) - (m & 15);
  int d2 = dr * dr + dc * dc;
  float val = 0.0f;
  if (d2 <= 229) {   // exact integer form of (m >= bound); boundary at d2==229
    const float fc = 6.2831853071795864f / (60.0f * 1.4142135623730951f);
    val = expf(cosf(fc * sqrtf((float)d2))) * 0.5f;
  }
  mod2[i] = f2b(val);
}

// ---------------- bf16 GEMM: out = A[M,K] @ Bt[N,K]^T + bias ----------------
// MODE 0: BM=256, 512 thr, A = x (fp32, converted in reg-staging); LDS-bounce epilogue
//         -> qfrag (scaled) / kfrag / vsw, fragment-ordered bf16.
// MODE 1: BM=128, 256 thr, A = attnb (bf16, gload_lds); f32 out [M][512].
template<int MODE>
__global__ __launch_bounds__(MODE == 0 ? 512 : 256) void gemm_bt(
    const float* __restrict__ Ax, const u16* __restrict__ A,
    const u16* __restrict__ Bt, const float* __restrict__ bvec,
    u16* __restrict__ oq, u16* __restrict__ ok, u16* __restrict__ ov,
    float* __restrict__ of) {
  constexpr int K = 512;
  constexpr int BM = (MODE == 0) ? 256 : 128;
  constexpr int NT = (MODE == 0) ? 512 : 256;
  constexpr int NBN = (MODE == 0) ? 12 : 4;
  constexpr int PER_XCD = (MODE == 0) ? 192 : 128;
  // MODE0: staging 48KB in low region; epilogue bounce uses full 64KB (8 x 8KB).
  __shared__ __align__(16) u16 SM[(MODE == 0) ? 32768 : 16384];
  u16* As = SM;
  u16* Bs = SM + BM * 64;
  const int tid = threadIdx.x, lane = tid & 63, w = tid >> 6;
  const int wr = w >> 1, wc = w & 1, lr = lane & 15, lg = lane >> 4;
  // XCD-chunked 1-D grid: bm-pair x all-bn contiguous per XCD (A+B L2-resident)
  const int logical = (blockIdx.x & 7) * PER_XCD + (blockIdx.x >> 3);
  const int bm = (logical / (2 * NBN)) * 2 + (logical & 1);
  const int bn = (logical % (2 * NBN)) >> 1;
  const u16* Bg = Bt + (size_t)bn * 128 * K;
  f32x4 acc[4][4];
#pragma unroll
  for (int m = 0; m < 4; ++m)
#pragma unroll
    for (int n = 0; n < 4; ++n) acc[m][n] = (f32x4){0.f, 0.f, 0.f, 0.f};

  for (int k0 = 0; k0 < K; k0 += 64) {
    if (MODE == 0) {
      // A: reg-stage fp32 x -> cvt -> swizzled ds_write (slot kc holds granule kc^(r&7))
#pragma unroll
      for (int it = 0; it < 4; ++it) {
        int chunk = it * NT + tid;            // (r, kc): r = chunk>>3, kc = chunk&7
        int r = chunk >> 3, kc = chunk & 7;
        int gg = kc ^ (r & 7);                // global granule for this LDS slot
        const float* src = Ax + (size_t)(bm * 256 + r) * K + k0 + gg * 8;
        float4 v0 = *(const float4*)src;
        float4 v1 = *(const float4*)(src + 4);
        u16 hb[8];
        hb[0] = f2bc(v0.x); hb[1] = f2bc(v0.y); hb[2] = f2bc(v0.z); hb[3] = f2bc(v0.w);
        hb[4] = f2bc(v1.x); hb[5] = f2bc(v1.y); hb[6] = f2bc(v1.z); hb[7] = f2bc(v1.w);
        *(uint4*)(As + chunk * 8) = *(const uint4*)hb;
      }
      // B: gload_lds with pre-swizzled source granule
#pragma unroll
      for (int it = 0; it < 2; ++it) {
        int chunk = it * NT + tid;
        int r = chunk >> 3, kc = chunk & 7;
        int kcs = kc ^ (r & 7);
        __builtin_amdgcn_global_load_lds(AS1(Bg + (size_t)r * K + k0 + kcs * 8),
                                         AS3(Bs + chunk * 8), 16, 0, 0);
      }
    } else {
      const u16* Ag = A + (size_t)bm * 128 * K;
#pragma unroll
      for (int it = 0; it < 4; ++it) {
        int chunk = it * NT + tid;
        int r = chunk >> 3, kc = chunk & 7;
        int kcs = kc ^ (r & 7);
        __builtin_amdgcn_global_load_lds(AS1(Ag + (size_t)r * K + k0 + kcs * 8),
                                         AS3(As + chunk * 8), 16, 0, 0);
        __builtin_amdgcn_global_load_lds(AS1(Bg + (size_t)r * K + k0 + kcs * 8),
                                         AS3(Bs + chunk * 8), 16, 0, 0);
      }
    }
    __syncthreads();
#pragma unroll
    for (int kk = 0; kk < 2; ++kk) {
      bf16x8 a[4], b[4];
#pragma unroll
      for (int m = 0; m < 4; ++m) {
        int ar = wr * 64 + m * 16 + lr;
        a[m] = *(const bf16x8*)&As[ar * 64 + (((kk * 4 + lg) ^ (lr & 7)) << 3)];
      }
#pragma unroll
      for (int n = 0; n < 4; ++n) {
        int br = wc * 64 + n * 16 + lr;
        b[n] = *(const bf16x8*)&Bs[br * 64 + (((kk * 4 + lg) ^ (lr & 7)) << 3)];
      }
#pragma unroll
      for (int m = 0; m < 4; ++m)
#pragma unroll
        for (int n = 0; n < 4; ++n)
          acc[m][n] = __builtin_amdgcn_mfma_f32_16x16x32_bf16(a[m], b[n], acc[m][n], 0, 0, 0);
    }
    __syncthreads();
  }

  if (MODE == 1) {
#pragma unroll
    for (int m = 0; m < 4; ++m)
#pragma unroll
      for (int n = 0; n < 4; ++n)
#pragma unroll
        for (int r = 0; r < 4; ++r) {
          int row = bm * BM + wr * 64 + m * 16 + lg * 4 + r;
          int col = bn * 128 + wc * 64 + n * 16 + lr;
          of[(size_t)row * CDIM + col] = acc[m][n][r] + bvec[col];
        }
    return;
  }

  // ---- MODE 0 epilogue: bounce via per-wave swizzled 64x64 bf16 LDS tile ----
  const int typ = bn >> 2;                 // 0=Q, 1=K, 2=V
  const int col0 = bn * 128 + wc * 64;
  const int row0 = bm * 256 + wr * 64;
  char* Tb = (char*)SM + w * 8192;         // 8 KB per wave (staging region is dead)

#pragma unroll
  for (int n = 0; n < 4; ++n) {
    float bv = bvec[col0 + n * 16 + lr];
#pragma unroll
    for (int m = 0; m < 4; ++m)
#pragma unroll
      for (int r = 0; r < 4; ++r) {
        float v = acc[m][n][r] + bv;
        if (typ == 0) v *= QSCALE;
        int row_l, col_l;
        if (typ < 2) { row_l = m * 16 + lg * 4 + r; col_l = n * 16 + lr; }
        else         { row_l = n * 16 + lr;         col_l = m * 16 + lg * 4 + r; }  // V: transposed
        int byte = row_l * 128 + ((((col_l >> 3) ^ (row_l & 7)) << 4) | ((col_l & 7) << 1));
        *(u16*)(Tb + byte) = f2b(v);
      }
  }
  asm volatile("" ::: "memory");   // pin LDS write->read order (strict-aliasing guard)
  // wave-local tile: DS pipe is in-order within a wave; no barrier needed
  if (typ < 2) {
    // Q/K readback: lane = token row; 8 x {ds_read_b128, coalesced 16B store}
    int tok = row0 + lane;
    int tokb = tok >> 8;
    u16* obase = (typ == 0) ? oq : ok;
#pragma unroll
    for (int G = 0; G < 8; ++G) {
      int hl = G >> 2, q = G & 3;
      uint4 v = *(const uint4*)(Tb + lane * 128 + ((G ^ (lane & 7)) << 4));
      int hh = ((col0 >> 5) & 15) + hl;     // head index
      size_t a = ((((size_t)tokb * 16 + hh) * 16 + ((tok >> 4) & 15)) * 64 +
                  ((tok & 15) | (q << 4))) * 8;
      *(uint4*)(obase + a) = v;
    }
  } else {
    // V readback: transposed tile; swizzles cancel -> sequential granules
    int tl0 = row0 & 255, tokb = row0 >> 8;
    int hl = lane >> 5, t = (lane >> 3) & 3, c = lane & 7;
    int hh = ((col0 >> 5) & 15) + hl;       // head index
#pragma unroll
    for (int i = 0; i < 8; ++i) {
      int d = i * 4 + t;
      uint4 v = *(const uint4*)(Tb + (hl * 32 + d) * 128 + (c << 4));
      size_t a = (((size_t)tokb * 16 + hh) * 32 + d) * 256 + tl0 + c * 8;
      *(uint4*)(ov + a) = v;
    }
  }
}

// ---------------- fused attention: 512-thread block = (b, h, qpair), 8 waves ----------------
__global__ __launch_bounds__(512, 4) void attn_kernel(const u16* __restrict__ qfrag,
                                                      const u16* __restrict__ kfrag,
                                                      const u16* __restrict__ vsw,
                                                      const u16* __restrict__ bias2,
                                                      const u16* __restrict__ mod2,
                                                      u16* __restrict__ attnout) {
  __shared__ __align__(16) u16 SM[24576];
  const int logical = (blockIdx.x & 7) * 512 + (blockIdx.x >> 3);   // 4096 blocks
  const int h = logical >> 8;           // 2 heads per XCD (bias/mod L2-resident)
  const int b = (logical >> 1) & 127;   // qpair-adjacent -> K/V L2 reuse
  const int qpair = logical & 1;
  const int tid = threadIdx.x, lane = tid & 63, w = tid >> 6;
  const int lr = lane & 15, lg = lane >> 4;
  const int rb = qpair * 8 + w;         // this wave's row-block (16 q rows)
  const int bhid = b * 16 + h;

  const u16* kg = kfrag + (size_t)bhid * 8192;
  const u16* vg = vsw + (size_t)bhid * 8192;
#pragma unroll
  for (int it = 0; it < 2; ++it) {
    __builtin_amdgcn_global_load_lds(AS1(kg + (it * 512 + tid) * 8),
                                     AS3(SM + (it * 512 + tid) * 8), 16, 0, 0);
    __builtin_amdgcn_global_load_lds(AS1(vg + (it * 512 + tid) * 8),
                                     AS3(SM + 8192 + (it * 512 + tid) * 8), 16, 0, 0);
  }
  bf16x8 qf = *(const bf16x8*)(qfrag + ((size_t)bhid * 16 + rb) * 512 + lane * 8);
  __syncthreads();

  const u16* bias_base = bias2 + (((size_t)h * 16 + rb) * 64 + lane) * 64;
  const u16* mod_base  = mod2 + ((size_t)rb * 64 + lane) * 64;
  char* Pbase = (char*)SM + 32768 + w * 2048;
  const char* Vb = (const char*)(SM + 8192);

  // S^T = K Q^T + bias : full 16 tiles, per-quarter transient bias loads
  f32x4 s[16];
#pragma unroll
  for (int q = 0; q < 4; ++q) {
    u32 bw8[8];
    {
      const uint4* bp = (const uint4*)(bias_base + q * 16);
      *(uint4*)&bw8[0] = bp[0]; *(uint4*)&bw8[4] = bp[1];
    }
#pragma unroll
    for (int tl = 0; tl < 4; ++tl) {
      int t = q * 4 + tl;
      bf16x8 kf = *(const bf16x8*)(SM + (t * 64 + lane) * 8);
      f32x4 c;
      c[0] = bf_lo(bw8[tl * 2]);     c[1] = bf_hi(bw8[tl * 2]);
      c[2] = bf_lo(bw8[tl * 2 + 1]); c[3] = bf_hi(bw8[tl * 2 + 1]);
      s[t] = __builtin_amdgcn_mfma_f32_16x16x32_bf16(kf, qf, c, 0, 0, 0);
    }
  }

  // softmax over m (log2 domain): 4 parallel max chains + 2 shuffles
  float mr0 = s[0][0], mr1 = s[0][1], mr2 = s[0][2], mr3 = s[0][3];
#pragma unroll
  for (int t = 1; t < 16; ++t) {
    mr0 = fmaxf(mr0, s[t][0]); mr1 = fmaxf(mr1, s[t][1]);
    mr2 = fmaxf(mr2, s[t][2]); mr3 = fmaxf(mr3, s[t][3]);
  }
  float mx = fmaxf(fmaxf(mr0, mr1), fmaxf(mr2, mr3));
  mx = fmaxf(mx, __shfl_xor(mx, 16, 64));
  mx = fmaxf(mx, __shfl_xor(mx, 32, 64));
  float s0 = 0.f, s1 = 0.f, s2 = 0.f, s3 = 0.f;
#pragma unroll
  for (int t = 0; t < 16; ++t) {
    s[t][0] = ex2(s[t][0] - mx); s0 += s[t][0];
    s[t][1] = ex2(s[t][1] - mx); s1 += s[t][1];
    s[t][2] = ex2(s[t][2] - mx); s2 += s[t][2];
    s[t][3] = ex2(s[t][3] - mx); s3 += s[t][3];
  }
  float sm = (s0 + s1) + (s2 + s3);
  sm += __shfl_xor(sm, 16, 64);
  sm += __shfl_xor(sm, 32, 64);
  sm = __builtin_amdgcn_rcpf(sm);   // own-lane: denominator for query n = lr (pre-pack norm)

  // quarter-partitioned pack (normalized P, mod applied) + PV
  f32x4 o0 = (f32x4){0.f, 0.f, 0.f, 0.f};
  f32x4 o1 = (f32x4){0.f, 0.f, 0.f, 0.f};
#pragma unroll
  for (int q = 0; q < 4; ++q) {
    u32 mw8[8];
    {
      const uint4* mp = (const uint4*)(mod_base + q * 16);
      *(uint4*)&mw8[0] = mp[0]; *(uint4*)&mw8[4] = mp[1];
    }
#pragma unroll
    for (int tl = 0; tl < 4; ++tl) {
      int t = q * 4 + tl;
      u16 pk[4];
#pragma unroll
      for (int r = 0; r < 4; ++r) {
        u32 wd = mw8[tl * 2 + (r >> 1)];
        float mf = (r & 1) ? bf_hi(wd) : bf_lo(wd);
        pk[r] = f2bc(s[t][r] * sm * mf);
      }
      int hi2 = (t * 2 + (lg >> 1)) & 3;
      *(uint2*)(Pbase + ((t >> 1) & 1) * 1024 + ((hi2 << 4) | lr) * 16 + (lg & 1) * 8)
          = *(const uint2*)pk;
    }
    asm volatile("" ::: "memory");   // pack stores must precede PV loads
#pragma unroll
    for (int kl = 0; kl < 2; ++kl) {
      bf16x8 pa = *(const bf16x8*)(Pbase + kl * 1024 + lane * 16);
      int cv = ((q * 2 + kl) * 4 + lg) ^ (lr & 7);
      bf16x8 v0 = *(const bf16x8*)(Vb + lr * 512 + cv * 16);
      bf16x8 v1 = *(const bf16x8*)(Vb + (16 + lr) * 512 + cv * 16);
      o0 = __builtin_amdgcn_mfma_f32_16x16x32_bf16(pa, v0, o0, 0, 0, 0);
      o1 = __builtin_amdgcn_mfma_f32_16x16x32_bf16(pa, v1, o1, 0, 0, 0);
    }
    asm volatile("" ::: "memory");   // PV loads must precede next quarter's pack (WAR)
  }

  u16* orow = attnout + (size_t)(b * TOK + rb * 16) * CDIM + h * 32;
#pragma unroll
  for (int r = 0; r < 4; ++r) {
    orow[(size_t)(lg * 4 + r) * CDIM + lr] = f2bc(o0[r]);
    orow[(size_t)(lg * 4 + r) * CDIM + 16 + lr] = f2bc(o1[r]);
  }
}

// ---------------- launch ----------------
extern "C" void kernel_launch(void* const* d_in, const int* in_sizes, int n_in,
                              void* d_out, int out_size, void* d_ws, size_t ws_size,
                              hipStream_t stream) {
  const float* x      = (const float*)d_in[0];
  const float* qkv_w  = (const float*)d_in[1];
  const float* qkv_b  = (const float*)d_in[2];
  const float* proj_w = (const float*)d_in[3];
  const float* proj_b = (const float*)d_in[4];
  const float* rpb    = (const float*)d_in[5];

  char* ws = (char*)d_ws;
  u16* qkvwb  = (u16*)(ws + 33554432);      //  1,572,864 B
  u16* projwb = (u16*)(ws + 35127296);      //    524,288 B
  u16* qfrag  = (u16*)(ws + 35651584);      // 33,554,432 B
  u16* kfrag  = (u16*)(ws + 69206016);      // 33,554,432 B
  u16* vswb   = (u16*)(ws + 102760448);     // 33,554,432 B
  u16* attnb  = (u16*)(ws + 136314880);     // 33,554,432 B
  u16* bias2  = (u16*)(ws + 169869312);     //  2,097,152 B
  u16* mod2   = (u16*)(ws + 171966464);     //    131,072 B

  cvt_bf16_kernel<<<384, 256, 0, stream>>>(qkv_w, qkvwb, 1536 * 512);
  cvt_bf16_kernel<<<128, 256, 0, stream>>>(proj_w, projwb, 512 * 512);
  build_bias2_kernel<<<4096, 256, 0, stream>>>(rpb, bias2);
  build_mod2_kernel<<<256, 256, 0, stream>>>(mod2);

  gemm_bt<0><<<1536, 512, 0, stream>>>(x, nullptr, qkvwb, qkv_b,
                                       qfrag, kfrag, vswb, nullptr);
  attn_kernel<<<4096, 512, 0, stream>>>(qfrag, kfrag, vswb, bias2, mod2, attnb);
  gemm_bt<1><<<1024, 256, 0, stream>>>(nullptr, attnb, projwb, proj_b,
                                       nullptr, nullptr, nullptr, (float*)d_out);
}

// Round 18
// 201.706 us; speedup vs baseline: 1.1907x; 1.0782x over previous
//
#include <hip/hip_runtime.h>
#include <hip/hip_bf16.h>

typedef unsigned short u16;
typedef unsigned int u32;
typedef __bf16 bf16x8 __attribute__((ext_vector_type(8)));
typedef float f32x4 __attribute__((ext_vector_type(4)));

#define AS1(p) ((const __attribute__((address_space(1))) void*)(p))
#define AS3(p) ((__attribute__((address_space(3))) void*)(p))

#define TOK   256
#define CDIM  512
#define QKVC  1536
#define LOG2E 1.4426950408889634f
#define QSCALE (0.17677669529663687f * 1.4426950408889634f)  // D^-0.5 * log2e

__device__ __forceinline__ u16 f2b(float f) {
  unsigned u = __float_as_uint(f);
  unsigned r = (u + 0x7fffu + ((u >> 16) & 1u)) >> 16;
  return (u16)r;
}
__device__ __forceinline__ u16 f2bc(float f) {
  __bf16 h = (__bf16)f;
  u16 u;
  __builtin_memcpy(&u, &h, 2);
  return u;
}
__device__ __forceinline__ float bf_lo(u32 wd) { return __uint_as_float(wd << 16); }
__device__ __forceinline__ float bf_hi(u32 wd) { return __uint_as_float(wd & 0xffff0000u); }
__device__ __forceinline__ float ex2(float x) {
  float r;
  asm("v_exp_f32 %0, %1" : "=v"(r) : "v"(x));
  return r;
}

// ---------------- fused preamble: weight cvt + bias2 + mod2 tables ----------------
// blocks [0,384): qkv_w fp32->bf16 (786432 elems, 8/thread)
// blocks [384,512): proj_w fp32->bf16 (262144 elems)
// blocks [512,4608): bias2 S^T-fragment table (2^20 entries, *log2e)
// blocks [4608,4864): mod2 S^T-fragment table (65536 entries)
__global__ __launch_bounds__(256) void prep_kernel(const float* __restrict__ qkv_w,
                                                   const float* __restrict__ proj_w,
                                                   const float* __restrict__ rpb,
                                                   u16* __restrict__ qkvwb,
                                                   u16* __restrict__ projwb,
                                                   u16* __restrict__ bias2,
                                                   u16* __restrict__ mod2) {
  const int blk = blockIdx.x, tid = threadIdx.x;
  if (blk < 512) {
    const float* in = (blk < 384) ? qkv_w : proj_w;
    u16* out = (blk < 384) ? qkvwb : projwb;
    int base = (blk < 384) ? blk : (blk - 384);
    int i = (base * 256 + tid) * 8;
    float4 a = *(const float4*)(in + i);
    float4 b = *(const float4*)(in + i + 4);
    u16 h[8];
    h[0] = f2b(a.x); h[1] = f2b(a.y); h[2] = f2b(a.z); h[3] = f2b(a.w);
    h[4] = f2b(b.x); h[5] = f2b(b.y); h[6] = f2b(b.z); h[7] = f2b(b.w);
    *(uint4*)(out + i) = *(const uint4*)h;
  } else if (blk < 4608) {
    int i = (blk - 512) * 256 + tid;   // 16*16*64*64 = 2^20
    int tr = i & 63, lane = (i >> 6) & 63, rb = (i >> 12) & 15, h = i >> 16;
    int t = tr >> 2, r = tr & 3;
    int n = rb * 16 + (lane & 15);
    int m = t * 16 + (lane >> 4) * 4 + r;
    int idx = ((n >> 4) - (m >> 4) + 15) * 31 + ((n & 15) - (m & 15) + 15);
    bias2[i] = f2b(rpb[idx * 16 + h] * LOG2E);
  } else {
    int i = (blk - 4608) * 256 + tid;  // 16*64*64 = 65536
    int tr = i & 63, lane = (i >> 6) & 63, rb = i >> 12;
    int t = tr >> 2, r = tr & 3;
    int n = rb * 16 + (lane & 15);
    int m = t * 16 + (lane >> 4) * 4 + r;
    int dr = (n >> 4) - (m >> 4), dc = (n & 15) - (m & 15);
    int d2 = dr * dr + dc * dc;
    float val = 0.0f;
    if (d2 <= 229) {   // exact integer form of (m >= bound); boundary at d2==229
      const float fc = 6.2831853071795864f / (60.0f * 1.4142135623730951f);
      val = expf(cosf(fc * sqrtf((float)d2))) * 0.5f;
    }
    mod2[i] = f2b(val);
  }
}

// ---------------- bf16 GEMM: out = A[M,K] @ Bt[N,K]^T + bias ----------------
// MODE 0: BM=256, 512 thr, A = x (fp32, converted in reg-staging); LDS-bounce epilogue
//         -> qfrag (scaled) / kfrag / vsw, fragment-ordered bf16.
// MODE 1: BM=128, 256 thr, A = attnb (bf16, gload_lds); f32 out [M][512].
template<int MODE>
__global__ __launch_bounds__(MODE == 0 ? 512 : 256) void gemm_bt(
    const float* __restrict__ Ax, const u16* __restrict__ A,
    const u16* __restrict__ Bt, const float* __restrict__ bvec,
    u16* __restrict__ oq, u16* __restrict__ ok, u16* __restrict__ ov,
    float* __restrict__ of) {
  constexpr int K = 512;
  constexpr int BM = (MODE == 0) ? 256 : 128;
  constexpr int NT = (MODE == 0) ? 512 : 256;
  constexpr int NBN = (MODE == 0) ? 12 : 4;
  constexpr int PER_XCD = (MODE == 0) ? 192 : 128;
  // MODE0: staging 48KB in low region; epilogue bounce uses full 64KB (8 x 8KB).
  __shared__ __align__(16) u16 SM[(MODE == 0) ? 32768 : 16384];
  u16* As = SM;
  u16* Bs = SM + BM * 64;
  const int tid = threadIdx.x, lane = tid & 63, w = tid >> 6;
  const int wr = w >> 1, wc = w & 1, lr = lane & 15, lg = lane >> 4;
  // XCD-chunked 1-D grid: bm-pair x all-bn contiguous per XCD (A+B L2-resident)
  const int logical = (blockIdx.x & 7) * PER_XCD + (blockIdx.x >> 3);
  const int bm = (logical / (2 * NBN)) * 2 + (logical & 1);
  const int bn = (logical % (2 * NBN)) >> 1;
  const u16* Bg = Bt + (size_t)bn * 128 * K;
  f32x4 acc[4][4];
#pragma unroll
  for (int m = 0; m < 4; ++m)
#pragma unroll
    for (int n = 0; n < 4; ++n) acc[m][n] = (f32x4){0.f, 0.f, 0.f, 0.f};

  for (int k0 = 0; k0 < K; k0 += 64) {
    if (MODE == 0) {
      // A: reg-stage fp32 x -> cvt -> swizzled ds_write (slot kc holds granule kc^(r&7))
#pragma unroll
      for (int it = 0; it < 4; ++it) {
        int chunk = it * NT + tid;            // (r, kc): r = chunk>>3, kc = chunk&7
        int r = chunk >> 3, kc = chunk & 7;
        int gg = kc ^ (r & 7);                // global granule for this LDS slot
        const float* src = Ax + (size_t)(bm * 256 + r) * K + k0 + gg * 8;
        float4 v0 = *(const float4*)src;
        float4 v1 = *(const float4*)(src + 4);
        u16 hb[8];
        hb[0] = f2bc(v0.x); hb[1] = f2bc(v0.y); hb[2] = f2bc(v0.z); hb[3] = f2bc(v0.w);
        hb[4] = f2bc(v1.x); hb[5] = f2bc(v1.y); hb[6] = f2bc(v1.z); hb[7] = f2bc(v1.w);
        *(uint4*)(As + chunk * 8) = *(const uint4*)hb;
      }
      // B: gload_lds with pre-swizzled source granule
#pragma unroll
      for (int it = 0; it < 2; ++it) {
        int chunk = it * NT + tid;
        int r = chunk >> 3, kc = chunk & 7;
        int kcs = kc ^ (r & 7);
        __builtin_amdgcn_global_load_lds(AS1(Bg + (size_t)r * K + k0 + kcs * 8),
                                         AS3(Bs + chunk * 8), 16, 0, 0);
      }
    } else {
      const u16* Ag = A + (size_t)bm * 128 * K;
#pragma unroll
      for (int it = 0; it < 4; ++it) {
        int chunk = it * NT + tid;
        int r = chunk >> 3, kc = chunk & 7;
        int kcs = kc ^ (r & 7);
        __builtin_amdgcn_global_load_lds(AS1(Ag + (size_t)r * K + k0 + kcs * 8),
                                         AS3(As + chunk * 8), 16, 0, 0);
        __builtin_amdgcn_global_load_lds(AS1(Bg + (size_t)r * K + k0 + kcs * 8),
                                         AS3(Bs + chunk * 8), 16, 0, 0);
      }
    }
    __syncthreads();
#pragma unroll
    for (int kk = 0; kk < 2; ++kk) {
      bf16x8 a[4], b[4];
#pragma unroll
      for (int m = 0; m < 4; ++m) {
        int ar = wr * 64 + m * 16 + lr;
        a[m] = *(const bf16x8*)&As[ar * 64 + (((kk * 4 + lg) ^ (lr & 7)) << 3)];
      }
#pragma unroll
      for (int n = 0; n < 4; ++n) {
        int br = wc * 64 + n * 16 + lr;
        b[n] = *(const bf16x8*)&Bs[br * 64 + (((kk * 4 + lg) ^ (lr & 7)) << 3)];
      }
#pragma unroll
      for (int m = 0; m < 4; ++m)
#pragma unroll
        for (int n = 0; n < 4; ++n)
          acc[m][n] = __builtin_amdgcn_mfma_f32_16x16x32_bf16(a[m], b[n], acc[m][n], 0, 0, 0);
    }
    __syncthreads();
  }

  if (MODE == 1) {
#pragma unroll
    for (int m = 0; m < 4; ++m)
#pragma unroll
      for (int n = 0; n < 4; ++n)
#pragma unroll
        for (int r = 0; r < 4; ++r) {
          int row = bm * BM + wr * 64 + m * 16 + lg * 4 + r;
          int col = bn * 128 + wc * 64 + n * 16 + lr;
          of[(size_t)row * CDIM + col] = acc[m][n][r] + bvec[col];
        }
    return;
  }

  // ---- MODE 0 epilogue: bounce via per-wave swizzled 64x64 bf16 LDS tile ----
  const int typ = bn >> 2;                 // 0=Q, 1=K, 2=V
  const int col0 = bn * 128 + wc * 64;
  const int row0 = bm * 256 + wr * 64;
  char* Tb = (char*)SM + w * 8192;         // 8 KB per wave (staging region is dead)

#pragma unroll
  for (int n = 0; n < 4; ++n) {
    float bv = bvec[col0 + n * 16 + lr];
#pragma unroll
    for (int m = 0; m < 4; ++m)
#pragma unroll
      for (int r = 0; r < 4; ++r) {
        float v = acc[m][n][r] + bv;
        if (typ == 0) v *= QSCALE;
        int row_l, col_l;
        if (typ < 2) { row_l = m * 16 + lg * 4 + r; col_l = n * 16 + lr; }
        else         { row_l = n * 16 + lr;         col_l = m * 16 + lg * 4 + r; }  // V: transposed
        int byte = row_l * 128 + ((((col_l >> 3) ^ (row_l & 7)) << 4) | ((col_l & 7) << 1));
        *(u16*)(Tb + byte) = f2b(v);
      }
  }
  asm volatile("" ::: "memory");   // pin LDS write->read order (strict-aliasing guard)
  // wave-local tile: DS pipe is in-order within a wave; no barrier needed
  if (typ < 2) {
    // Q/K readback: lane = token row; 8 x {ds_read_b128, coalesced 16B store}
    int tok = row0 + lane;
    int tokb = tok >> 8;
    u16* obase = (typ == 0) ? oq : ok;
#pragma unroll
    for (int G = 0; G < 8; ++G) {
      int hl = G >> 2, q = G & 3;
      uint4 v = *(const uint4*)(Tb + lane * 128 + ((G ^ (lane & 7)) << 4));
      int hh = ((col0 >> 5) & 15) + hl;     // head index
      size_t a = ((((size_t)tokb * 16 + hh) * 16 + ((tok >> 4) & 15)) * 64 +
                  ((tok & 15) | (q << 4))) * 8;
      *(uint4*)(obase + a) = v;
    }
  } else {
    // V readback: transposed tile; swizzles cancel -> sequential granules
    int tl0 = row0 & 255, tokb = row0 >> 8;
    int hl = lane >> 5, t = (lane >> 3) & 3, c = lane & 7;
    int hh = ((col0 >> 5) & 15) + hl;       // head index
#pragma unroll
    for (int i = 0; i < 8; ++i) {
      int d = i * 4 + t;
      uint4 v = *(const uint4*)(Tb + (hl * 32 + d) * 128 + (c << 4));
      size_t a = (((size_t)tokb * 16 + hh) * 32 + d) * 256 + tl0 + c * 8;
      *(uint4*)(ov + a) = v;
    }
  }
}

// ---------------- fused attention: 512-thread block = (b, h, qpair), 8 waves ----------------
__global__ __launch_bounds__(512, 4) void attn_kernel(const u16* __restrict__ qfrag,
                                                      const u16* __restrict__ kfrag,
                                                      const u16* __restrict__ vsw,
                                                      const u16* __restrict__ bias2,
                                                      const u16* __restrict__ mod2,
                                                      u16* __restrict__ attnout) {
  __shared__ __align__(16) u16 SM[24576];
  const int logical = (blockIdx.x & 7) * 512 + (blockIdx.x >> 3);   // 4096 blocks
  const int h = logical >> 8;           // 2 heads per XCD (bias/mod L2-resident)
  const int b = (logical >> 1) & 127;   // qpair-adjacent -> K/V L2 reuse
  const int qpair = logical & 1;
  const int tid = threadIdx.x, lane = tid & 63, w = tid >> 6;
  const int lr = lane & 15, lg = lane >> 4;
  const int rb = qpair * 8 + w;         // this wave's row-block (16 q rows)
  const int bhid = b * 16 + h;

  const u16* kg = kfrag + (size_t)bhid * 8192;
  const u16* vg = vsw + (size_t)bhid * 8192;
#pragma unroll
  for (int it = 0; it < 2; ++it) {
    __builtin_amdgcn_global_load_lds(AS1(kg + (it * 512 + tid) * 8),
                                     AS3(SM + (it * 512 + tid) * 8), 16, 0, 0);
    __builtin_amdgcn_global_load_lds(AS1(vg + (it * 512 + tid) * 8),
                                     AS3(SM + 8192 + (it * 512 + tid) * 8), 16, 0, 0);
  }
  bf16x8 qf = *(const bf16x8*)(qfrag + ((size_t)bhid * 16 + rb) * 512 + lane * 8);
  __syncthreads();

  const u16* bias_base = bias2 + (((size_t)h * 16 + rb) * 64 + lane) * 64;
  const u16* mod_base  = mod2 + ((size_t)rb * 64 + lane) * 64;
  char* Pbase = (char*)SM + 32768 + w * 2048;
  const char* Vb = (const char*)(SM + 8192);

  // S^T = K Q^T + bias : full 16 tiles, per-quarter transient bias loads
  f32x4 s[16];
#pragma unroll
  for (int q = 0; q < 4; ++q) {
    u32 bw8[8];
    {
      const uint4* bp = (const uint4*)(bias_base + q * 16);
      *(uint4*)&bw8[0] = bp[0]; *(uint4*)&bw8[4] = bp[1];
    }
    __builtin_amdgcn_s_setprio(1);   // T5: favor MFMA-issuing wave (independent waves)
#pragma unroll
    for (int tl = 0; tl < 4; ++tl) {
      int t = q * 4 + tl;
      bf16x8 kf = *(const bf16x8*)(SM + (t * 64 + lane) * 8);
      f32x4 c;
      c[0] = bf_lo(bw8[tl * 2]);     c[1] = bf_hi(bw8[tl * 2]);
      c[2] = bf_lo(bw8[tl * 2 + 1]); c[3] = bf_hi(bw8[tl * 2 + 1]);
      s[t] = __builtin_amdgcn_mfma_f32_16x16x32_bf16(kf, qf, c, 0, 0, 0);
    }
    __builtin_amdgcn_s_setprio(0);
  }

  // softmax over m (log2 domain): 4 parallel max chains + 2 shuffles
  float mr0 = s[0][0], mr1 = s[0][1], mr2 = s[0][2], mr3 = s[0][3];
#pragma unroll
  for (int t = 1; t < 16; ++t) {
    mr0 = fmaxf(mr0, s[t][0]); mr1 = fmaxf(mr1, s[t][1]);
    mr2 = fmaxf(mr2, s[t][2]); mr3 = fmaxf(mr3, s[t][3]);
  }
  float mx = fmaxf(fmaxf(mr0, mr1), fmaxf(mr2, mr3));
  mx = fmaxf(mx, __shfl_xor(mx, 16, 64));
  mx = fmaxf(mx, __shfl_xor(mx, 32, 64));
  float s0 = 0.f, s1 = 0.f, s2 = 0.f, s3 = 0.f;
#pragma unroll
  for (int t = 0; t < 16; ++t) {
    s[t][0] = ex2(s[t][0] - mx); s0 += s[t][0];
    s[t][1] = ex2(s[t][1] - mx); s1 += s[t][1];
    s[t][2] = ex2(s[t][2] - mx); s2 += s[t][2];
    s[t][3] = ex2(s[t][3] - mx); s3 += s[t][3];
  }
  float sm = (s0 + s1) + (s2 + s3);
  sm += __shfl_xor(sm, 16, 64);
  sm += __shfl_xor(sm, 32, 64);
  sm = __builtin_amdgcn_rcpf(sm);   // own-lane: denominator for query n = lr (pre-pack norm)

  // quarter-partitioned pack (normalized P, mod applied) + PV
  f32x4 o0 = (f32x4){0.f, 0.f, 0.f, 0.f};
  f32x4 o1 = (f32x4){0.f, 0.f, 0.f, 0.f};
#pragma unroll
  for (int q = 0; q < 4; ++q) {
    u32 mw8[8];
    {
      const uint4* mp = (const uint4*)(mod_base + q * 16);
      *(uint4*)&mw8[0] = mp[0]; *(uint4*)&mw8[4] = mp[1];
    }
#pragma unroll
    for (int tl = 0; tl < 4; ++tl) {
      int t = q * 4 + tl;
      u16 pk[4];
#pragma unroll
      for (int r = 0; r < 4; ++r) {
        u32 wd = mw8[tl * 2 + (r >> 1)];
        float mf = (r & 1) ? bf_hi(wd) : bf_lo(wd);
        pk[r] = f2bc(s[t][r] * sm * mf);
      }
      int hi2 = (t * 2 + (lg >> 1)) & 3;
      *(uint2*)(Pbase + ((t >> 1) & 1) * 1024 + ((hi2 << 4) | lr) * 16 + (lg & 1) * 8)
          = *(const uint2*)pk;
    }
    asm volatile("" ::: "memory");   // pack stores must precede PV loads
    __builtin_amdgcn_s_setprio(1);   // T5
#pragma unroll
    for (int kl = 0; kl < 2; ++kl) {
      bf16x8 pa = *(const bf16x8*)(Pbase + kl * 1024 + lane * 16);
      int cv = ((q * 2 + kl) * 4 + lg) ^ (lr & 7);
      bf16x8 v0 = *(const bf16x8*)(Vb + lr * 512 + cv * 16);
      bf16x8 v1 = *(const bf16x8*)(Vb + (16 + lr) * 512 + cv * 16);
      o0 = __builtin_amdgcn_mfma_f32_16x16x32_bf16(pa, v0, o0, 0, 0, 0);
      o1 = __builtin_amdgcn_mfma_f32_16x16x32_bf16(pa, v1, o1, 0, 0, 0);
    }
    __builtin_amdgcn_s_setprio(0);
    asm volatile("" ::: "memory");   // PV loads must precede next quarter's pack (WAR)
  }

  u16* orow = attnout + (size_t)(b * TOK + rb * 16) * CDIM + h * 32;
#pragma unroll
  for (int r = 0; r < 4; ++r) {
    orow[(size_t)(lg * 4 + r) * CDIM + lr] = f2bc(o0[r]);
    orow[(size_t)(lg * 4 + r) * CDIM + 16 + lr] = f2bc(o1[r]);
  }
}

// ---------------- launch ----------------
extern "C" void kernel_launch(void* const* d_in, const int* in_sizes, int n_in,
                              void* d_out, int out_size, void* d_ws, size_t ws_size,
                              hipStream_t stream) {
  const float* x      = (const float*)d_in[0];
  const float* qkv_w  = (const float*)d_in[1];
  const float* qkv_b  = (const float*)d_in[2];
  const float* proj_w = (const float*)d_in[3];
  const float* proj_b = (const float*)d_in[4];
  const float* rpb    = (const float*)d_in[5];

  char* ws = (char*)d_ws;
  u16* qkvwb  = (u16*)(ws + 33554432);      //  1,572,864 B
  u16* projwb = (u16*)(ws + 35127296);      //    524,288 B
  u16* qfrag  = (u16*)(ws + 35651584);      // 33,554,432 B
  u16* kfrag  = (u16*)(ws + 69206016);      // 33,554,432 B
  u16* vswb   = (u16*)(ws + 102760448);     // 33,554,432 B
  u16* attnb  = (u16*)(ws + 136314880);     // 33,554,432 B
  u16* bias2  = (u16*)(ws + 169869312);     //  2,097,152 B
  u16* mod2   = (u16*)(ws + 171966464);     //    131,072 B

  prep_kernel<<<4864, 256, 0, stream>>>(qkv_w, proj_w, rpb, qkvwb, projwb, bias2, mod2);
  gemm_bt<0><<<1536, 512, 0, stream>>>(x, nullptr, qkvwb, qkv_b,
                                       qfrag, kfrag, vswb, nullptr);
  attn_kernel<<<4096, 512, 0, stream>>>(qfrag, kfrag, vswb, bias2, mod2, attnb);
  gemm_bt<1><<<1024, 256, 0, stream>>>(nullptr, attnb, projwb, proj_b,
                                       nullptr, nullptr, nullptr, (float*)d_out);
}

// Round 19
// 199.870 us; speedup vs baseline: 1.2017x; 1.0092x over previous
//
#include <hip/hip_runtime.h>
#include <hip/hip_bf16.h>

typedef unsigned short u16;
typedef unsigned int u32;
typedef __bf16 bf16x8 __attribute__((ext_vector_type(8)));
typedef float f32x4 __attribute__((ext_vector_type(4)));

#define AS1(p) ((const __attribute__((address_space(1))) void*)(p))
#define AS3(p) ((__attribute__((address_space(3))) void*)(p))

#define TOK   256
#define CDIM  512
#define QKVC  1536
#define LOG2E 1.4426950408889634f
#define QSCALE (0.17677669529663687f * 1.4426950408889634f)  // D^-0.5 * log2e

__device__ __forceinline__ u16 f2b(float f) {
  unsigned u = __float_as_uint(f);
  unsigned r = (u + 0x7fffu + ((u >> 16) & 1u)) >> 16;
  return (u16)r;
}
__device__ __forceinline__ u16 f2bc(float f) {
  __bf16 h = (__bf16)f;
  u16 u;
  __builtin_memcpy(&u, &h, 2);
  return u;
}
__device__ __forceinline__ float bf_lo(u32 wd) { return __uint_as_float(wd << 16); }
__device__ __forceinline__ float bf_hi(u32 wd) { return __uint_as_float(wd & 0xffff0000u); }
__device__ __forceinline__ float ex2(float x) {
  float r;
  asm("v_exp_f32 %0, %1" : "=v"(r) : "v"(x));
  return r;
}

// ---------------- fused preamble: weight cvt + bias2 + mod2 tables ----------------
__global__ __launch_bounds__(256) void prep_kernel(const float* __restrict__ qkv_w,
                                                   const float* __restrict__ proj_w,
                                                   const float* __restrict__ rpb,
                                                   u16* __restrict__ qkvwb,
                                                   u16* __restrict__ projwb,
                                                   u16* __restrict__ bias2,
                                                   u16* __restrict__ mod2) {
  const int blk = blockIdx.x, tid = threadIdx.x;
  if (blk < 512) {
    const float* in = (blk < 384) ? qkv_w : proj_w;
    u16* out = (blk < 384) ? qkvwb : projwb;
    int base = (blk < 384) ? blk : (blk - 384);
    int i = (base * 256 + tid) * 8;
    float4 a = *(const float4*)(in + i);
    float4 b = *(const float4*)(in + i + 4);
    u16 h[8];
    h[0] = f2b(a.x); h[1] = f2b(a.y); h[2] = f2b(a.z); h[3] = f2b(a.w);
    h[4] = f2b(b.x); h[5] = f2b(b.y); h[6] = f2b(b.z); h[7] = f2b(b.w);
    *(uint4*)(out + i) = *(const uint4*)h;
  } else if (blk < 4608) {
    int i = (blk - 512) * 256 + tid;   // 16*16*64*64 = 2^20
    int tr = i & 63, lane = (i >> 6) & 63, rb = (i >> 12) & 15, h = i >> 16;
    int t = tr >> 2, r = tr & 3;
    int n = rb * 16 + (lane & 15);
    int m = t * 16 + (lane >> 4) * 4 + r;
    int idx = ((n >> 4) - (m >> 4) + 15) * 31 + ((n & 15) - (m & 15) + 15);
    bias2[i] = f2b(rpb[idx * 16 + h] * LOG2E);
  } else {
    int i = (blk - 4608) * 256 + tid;  // 16*64*64 = 65536
    int tr = i & 63, lane = (i >> 6) & 63, rb = i >> 12;
    int t = tr >> 2, r = tr & 3;
    int n = rb * 16 + (lane & 15);
    int m = t * 16 + (lane >> 4) * 4 + r;
    int dr = (n >> 4) - (m >> 4), dc = (n & 15) - (m & 15);
    int d2 = dr * dr + dc * dc;
    float val = 0.0f;
    if (d2 <= 229) {   // exact integer form of (m >= bound); boundary at d2==229
      const float fc = 6.2831853071795864f / (60.0f * 1.4142135623730951f);
      val = expf(cosf(fc * sqrtf((float)d2))) * 0.5f;
    }
    mod2[i] = f2b(val);
  }
}

// ---------------- bf16 GEMM: out = A[M,K] @ Bt[N,K]^T + bias ----------------
// MODE 0: BM=256, 512 thr, A = x (fp32, converted in reg-staging); LDS-bounce epilogue
//         -> qfrag (scaled) / kfrag / vsw, fragment-ordered bf16.
// MODE 1: BM=128, 256 thr, A = attnb (bf16, gload_lds); f32 out (nontemporal).
template<int MODE>
__global__ __launch_bounds__(MODE == 0 ? 512 : 256) void gemm_bt(
    const float* __restrict__ Ax, const u16* __restrict__ A,
    const u16* __restrict__ Bt, const float* __restrict__ bvec,
    u16* __restrict__ oq, u16* __restrict__ ok, u16* __restrict__ ov,
    float* __restrict__ of) {
  constexpr int K = 512;
  constexpr int BM = (MODE == 0) ? 256 : 128;
  constexpr int NT = (MODE == 0) ? 512 : 256;
  constexpr int NBN = (MODE == 0) ? 12 : 4;
  constexpr int PER_XCD = (MODE == 0) ? 192 : 128;
  __shared__ __align__(16) u16 SM[(MODE == 0) ? 32768 : 16384];
  u16* As = SM;
  u16* Bs = SM + BM * 64;
  const int tid = threadIdx.x, lane = tid & 63, w = tid >> 6;
  const int wr = w >> 1, wc = w & 1, lr = lane & 15, lg = lane >> 4;
  // XCD-chunked 1-D grid: bm-pair x all-bn contiguous per XCD (A+B L2-resident)
  const int logical = (blockIdx.x & 7) * PER_XCD + (blockIdx.x >> 3);
  const int bm = (logical / (2 * NBN)) * 2 + (logical & 1);
  const int bn = (logical % (2 * NBN)) >> 1;
  const u16* Bg = Bt + (size_t)bn * 128 * K;
  f32x4 acc[4][4];
#pragma unroll
  for (int m = 0; m < 4; ++m)
#pragma unroll
    for (int n = 0; n < 4; ++n) acc[m][n] = (f32x4){0.f, 0.f, 0.f, 0.f};

  for (int k0 = 0; k0 < K; k0 += 64) {
    if (MODE == 0) {
      // A: reg-stage fp32 x -> cvt -> swizzled ds_write (slot kc holds granule kc^(r&7))
#pragma unroll
      for (int it = 0; it < 4; ++it) {
        int chunk = it * NT + tid;            // (r, kc): r = chunk>>3, kc = chunk&7
        int r = chunk >> 3, kc = chunk & 7;
        int gg = kc ^ (r & 7);                // global granule for this LDS slot
        const float* src = Ax + (size_t)(bm * 256 + r) * K + k0 + gg * 8;
        float4 v0 = *(const float4*)src;
        float4 v1 = *(const float4*)(src + 4);
        u16 hb[8];
        hb[0] = f2bc(v0.x); hb[1] = f2bc(v0.y); hb[2] = f2bc(v0.z); hb[3] = f2bc(v0.w);
        hb[4] = f2bc(v1.x); hb[5] = f2bc(v1.y); hb[6] = f2bc(v1.z); hb[7] = f2bc(v1.w);
        *(uint4*)(As + chunk * 8) = *(const uint4*)hb;
      }
      // B: gload_lds with pre-swizzled source granule
#pragma unroll
      for (int it = 0; it < 2; ++it) {
        int chunk = it * NT + tid;
        int r = chunk >> 3, kc = chunk & 7;
        int kcs = kc ^ (r & 7);
        __builtin_amdgcn_global_load_lds(AS1(Bg + (size_t)r * K + k0 + kcs * 8),
                                         AS3(Bs + chunk * 8), 16, 0, 0);
      }
    } else {
      const u16* Ag = A + (size_t)bm * 128 * K;
#pragma unroll
      for (int it = 0; it < 4; ++it) {
        int chunk = it * NT + tid;
        int r = chunk >> 3, kc = chunk & 7;
        int kcs = kc ^ (r & 7);
        __builtin_amdgcn_global_load_lds(AS1(Ag + (size_t)r * K + k0 + kcs * 8),
                                         AS3(As + chunk * 8), 16, 0, 0);
        __builtin_amdgcn_global_load_lds(AS1(Bg + (size_t)r * K + k0 + kcs * 8),
                                         AS3(Bs + chunk * 8), 16, 0, 0);
      }
    }
    __syncthreads();
#pragma unroll
    for (int kk = 0; kk < 2; ++kk) {
      bf16x8 a[4], b[4];
#pragma unroll
      for (int m = 0; m < 4; ++m) {
        int ar = wr * 64 + m * 16 + lr;
        a[m] = *(const bf16x8*)&As[ar * 64 + (((kk * 4 + lg) ^ (lr & 7)) << 3)];
      }
#pragma unroll
      for (int n = 0; n < 4; ++n) {
        int br = wc * 64 + n * 16 + lr;
        b[n] = *(const bf16x8*)&Bs[br * 64 + (((kk * 4 + lg) ^ (lr & 7)) << 3)];
      }
#pragma unroll
      for (int m = 0; m < 4; ++m)
#pragma unroll
        for (int n = 0; n < 4; ++n)
          acc[m][n] = __builtin_amdgcn_mfma_f32_16x16x32_bf16(a[m], b[n], acc[m][n], 0, 0, 0);
    }
    __syncthreads();
  }

  if (MODE == 1) {
#pragma unroll
    for (int m = 0; m < 4; ++m)
#pragma unroll
      for (int n = 0; n < 4; ++n)
#pragma unroll
        for (int r = 0; r < 4; ++r) {
          int row = bm * BM + wr * 64 + m * 16 + lg * 4 + r;
          int col = bn * 128 + wc * 64 + n * 16 + lr;
          __builtin_nontemporal_store(acc[m][n][r] + bvec[col],
                                      &of[(size_t)row * CDIM + col]);
        }
    return;
  }

  // ---- MODE 0 epilogue: bounce via per-wave swizzled 64x64 bf16 LDS tile ----
  const int typ = bn >> 2;                 // 0=Q, 1=K, 2=V
  const int col0 = bn * 128 + wc * 64;
  const int row0 = bm * 256 + wr * 64;
  char* Tb = (char*)SM + w * 8192;         // 8 KB per wave (staging region is dead)

#pragma unroll
  for (int n = 0; n < 4; ++n) {
    float bv = bvec[col0 + n * 16 + lr];
#pragma unroll
    for (int m = 0; m < 4; ++m)
#pragma unroll
      for (int r = 0; r < 4; ++r) {
        float v = acc[m][n][r] + bv;
        if (typ == 0) v *= QSCALE;
        int row_l, col_l;
        if (typ < 2) { row_l = m * 16 + lg * 4 + r; col_l = n * 16 + lr; }
        else         { row_l = n * 16 + lr;         col_l = m * 16 + lg * 4 + r; }  // V: transposed
        int byte = row_l * 128 + ((((col_l >> 3) ^ (row_l & 7)) << 4) | ((col_l & 7) << 1));
        *(u16*)(Tb + byte) = f2b(v);
      }
  }
  asm volatile("" ::: "memory");   // pin LDS write->read order (strict-aliasing guard)
  // wave-local tile: DS pipe is in-order within a wave; no barrier needed
  if (typ < 2) {
    // Q/K readback: lane = token row; 8 x {ds_read_b128, coalesced 16B store}
    int tok = row0 + lane;
    int tokb = tok >> 8;
    u16* obase = (typ == 0) ? oq : ok;
#pragma unroll
    for (int G = 0; G < 8; ++G) {
      int hl = G >> 2, q = G & 3;
      uint4 v = *(const uint4*)(Tb + lane * 128 + ((G ^ (lane & 7)) << 4));
      int hh = ((col0 >> 5) & 15) + hl;     // head index
      size_t a = ((((size_t)tokb * 16 + hh) * 16 + ((tok >> 4) & 15)) * 64 +
                  ((tok & 15) | (q << 4))) * 8;
      *(uint4*)(obase + a) = v;
    }
  } else {
    // V readback: transposed tile; swizzles cancel -> sequential granules
    int tl0 = row0 & 255, tokb = row0 >> 8;
    int hl = lane >> 5, t = (lane >> 3) & 3, c = lane & 7;
    int hh = ((col0 >> 5) & 15) + hl;       // head index
#pragma unroll
    for (int i = 0; i < 8; ++i) {
      int d = i * 4 + t;
      uint4 v = *(const uint4*)(Tb + (hl * 32 + d) * 128 + (c << 4));
      size_t a = (((size_t)tokb * 16 + hh) * 32 + d) * 256 + tl0 + c * 8;
      *(uint4*)(ov + a) = v;
    }
  }
}

// ---------------- fused attention: 512-thread block = (b, h, qpair), 8 waves ----------------
__global__ __launch_bounds__(512, 4) void attn_kernel(const u16* __restrict__ qfrag,
                                                      const u16* __restrict__ kfrag,
                                                      const u16* __restrict__ vsw,
                                                      const u16* __restrict__ bias2,
                                                      const u16* __restrict__ mod2,
                                                      u16* __restrict__ attnout) {
  __shared__ __align__(16) u16 SM[24576];
  const int logical = (blockIdx.x & 7) * 512 + (blockIdx.x >> 3);   // 4096 blocks
  const int h = logical >> 8;           // 2 heads per XCD (bias/mod L2-resident)
  const int b = (logical >> 1) & 127;   // qpair-adjacent -> K/V L2 reuse
  const int qpair = logical & 1;
  const int tid = threadIdx.x, lane = tid & 63, w = tid >> 6;
  const int lr = lane & 15, lg = lane >> 4;
  const int rb = qpair * 8 + w;         // this wave's row-block (16 q rows)
  const int bhid = b * 16 + h;

  const u16* kg = kfrag + (size_t)bhid * 8192;
  const u16* vg = vsw + (size_t)bhid * 8192;
#pragma unroll
  for (int it = 0; it < 2; ++it) {
    __builtin_amdgcn_global_load_lds(AS1(kg + (it * 512 + tid) * 8),
                                     AS3(SM + (it * 512 + tid) * 8), 16, 0, 0);
    __builtin_amdgcn_global_load_lds(AS1(vg + (it * 512 + tid) * 8),
                                     AS3(SM + 8192 + (it * 512 + tid) * 8), 16, 0, 0);
  }
  bf16x8 qf = *(const bf16x8*)(qfrag + ((size_t)bhid * 16 + rb) * 512 + lane * 8);
  __syncthreads();

  const u16* bias_base = bias2 + (((size_t)h * 16 + rb) * 64 + lane) * 64;
  const u16* mod_base  = mod2 + ((size_t)rb * 64 + lane) * 64;
  char* Pbase = (char*)SM + 32768 + w * 2048;
  const char* Vb = (const char*)(SM + 8192);

  // S^T = K Q^T + bias : full 16 tiles, per-quarter transient bias loads
  f32x4 s[16];
#pragma unroll
  for (int q = 0; q < 4; ++q) {
    u32 bw8[8];
    {
      const uint4* bp = (const uint4*)(bias_base + q * 16);
      *(uint4*)&bw8[0] = bp[0]; *(uint4*)&bw8[4] = bp[1];
    }
    __builtin_amdgcn_s_setprio(1);   // T5: favor MFMA-issuing wave (independent waves)
#pragma unroll
    for (int tl = 0; tl < 4; ++tl) {
      int t = q * 4 + tl;
      bf16x8 kf = *(const bf16x8*)(SM + (t * 64 + lane) * 8);
      f32x4 c;
      c[0] = bf_lo(bw8[tl * 2]);     c[1] = bf_hi(bw8[tl * 2]);
      c[2] = bf_lo(bw8[tl * 2 + 1]); c[3] = bf_hi(bw8[tl * 2 + 1]);
      s[t] = __builtin_amdgcn_mfma_f32_16x16x32_bf16(kf, qf, c, 0, 0, 0);
    }
    __builtin_amdgcn_s_setprio(0);
  }

  // softmax over m (log2 domain): 4 parallel max chains + 2 shuffles
  float mr0 = s[0][0], mr1 = s[0][1], mr2 = s[0][2], mr3 = s[0][3];
#pragma unroll
  for (int t = 1; t < 16; ++t) {
    mr0 = fmaxf(mr0, s[t][0]); mr1 = fmaxf(mr1, s[t][1]);
    mr2 = fmaxf(mr2, s[t][2]); mr3 = fmaxf(mr3, s[t][3]);
  }
  float mx = fmaxf(fmaxf(mr0, mr1), fmaxf(mr2, mr3));
  mx = fmaxf(mx, __shfl_xor(mx, 16, 64));
  mx = fmaxf(mx, __shfl_xor(mx, 32, 64));
  float s0 = 0.f, s1 = 0.f, s2 = 0.f, s3 = 0.f;
#pragma unroll
  for (int t = 0; t < 16; ++t) {
    s[t][0] = ex2(s[t][0] - mx); s0 += s[t][0];
    s[t][1] = ex2(s[t][1] - mx); s1 += s[t][1];
    s[t][2] = ex2(s[t][2] - mx); s2 += s[t][2];
    s[t][3] = ex2(s[t][3] - mx); s3 += s[t][3];
  }
  float sm = (s0 + s1) + (s2 + s3);
  sm += __shfl_xor(sm, 16, 64);
  sm += __shfl_xor(sm, 32, 64);
  sm = __builtin_amdgcn_rcpf(sm);   // own-lane: denominator for query n = lr (pre-pack norm)

  // quarter-partitioned pack (normalized P, mod applied) + PV
  f32x4 o0 = (f32x4){0.f, 0.f, 0.f, 0.f};
  f32x4 o1 = (f32x4){0.f, 0.f, 0.f, 0.f};
#pragma unroll
  for (int q = 0; q < 4; ++q) {
    u32 mw8[8];
    {
      const uint4* mp = (const uint4*)(mod_base + q * 16);
      *(uint4*)&mw8[0] = mp[0]; *(uint4*)&mw8[4] = mp[1];
    }
#pragma unroll
    for (int tl = 0; tl < 4; ++tl) {
      int t = q * 4 + tl;
      u16 pk[4];
#pragma unroll
      for (int r = 0; r < 4; ++r) {
        u32 wd = mw8[tl * 2 + (r >> 1)];
        float mf = (r & 1) ? bf_hi(wd) : bf_lo(wd);
        pk[r] = f2bc(s[t][r] * sm * mf);
      }
      int hi2 = (t * 2 + (lg >> 1)) & 3;
      *(uint2*)(Pbase + ((t >> 1) & 1) * 1024 + ((hi2 << 4) | lr) * 16 + (lg & 1) * 8)
          = *(const uint2*)pk;
    }
    asm volatile("" ::: "memory");   // pack stores must precede PV loads
    __builtin_amdgcn_s_setprio(1);   // T5
#pragma unroll
    for (int kl = 0; kl < 2; ++kl) {
      bf16x8 pa = *(const bf16x8*)(Pbase + kl * 1024 + lane * 16);
      int cv = ((q * 2 + kl) * 4 + lg) ^ (lr & 7);
      bf16x8 v0 = *(const bf16x8*)(Vb + lr * 512 + cv * 16);
      bf16x8 v1 = *(const bf16x8*)(Vb + (16 + lr) * 512 + cv * 16);
      o0 = __builtin_amdgcn_mfma_f32_16x16x32_bf16(pa, v0, o0, 0, 0, 0);
      o1 = __builtin_amdgcn_mfma_f32_16x16x32_bf16(pa, v1, o1, 0, 0, 0);
    }
    __builtin_amdgcn_s_setprio(0);
    asm volatile("" ::: "memory");   // PV loads must precede next quarter's pack (WAR)
  }

  // O-store bounce through dead P region: lg-XOR-swizzled 1KB/wave tile,
  // then one coalesced 16B store per lane (replaces 8 scattered u16 stores).
  u16* Ob = (u16*)Pbase;
#pragma unroll
  for (int r = 0; r < 4; ++r) {
    int row = lg * 4 + r;
    int gs0 = (lr >> 3) ^ lg;              // granule of d = lr
    int gs1 = (2 + (lr >> 3)) ^ lg;        // granule of d = 16+lr
    *(u16*)((char*)Ob + row * 64 + gs0 * 16 + (lr & 7) * 2) = f2bc(o0[r]);
    *(u16*)((char*)Ob + row * 64 + gs1 * 16 + (lr & 7) * 2) = f2bc(o1[r]);
  }
  asm volatile("" ::: "memory");   // O writes must precede readback
  {
    int row = lane >> 2, c = lane & 3;     // writer lg = row>>2 -> un-swizzle c^(row>>2)
    uint4 v = *(const uint4*)((const char*)Ob + row * 64 + ((c ^ (row >> 2)) << 4));
    u16* orow = attnout + (size_t)(b * TOK + rb * 16 + row) * CDIM + h * 32 + c * 8;
    *(uint4*)orow = v;
  }
}

// ---------------- launch ----------------
extern "C" void kernel_launch(void* const* d_in, const int* in_sizes, int n_in,
                              void* d_out, int out_size, void* d_ws, size_t ws_size,
                              hipStream_t stream) {
  const float* x      = (const float*)d_in[0];
  const float* qkv_w  = (const float*)d_in[1];
  const float* qkv_b  = (const float*)d_in[2];
  const float* proj_w = (const float*)d_in[3];
  const float* proj_b = (const float*)d_in[4];
  const float* rpb    = (const float*)d_in[5];

  char* ws = (char*)d_ws;
  u16* qkvwb  = (u16*)(ws + 33554432);      //  1,572,864 B
  u16* projwb = (u16*)(ws + 35127296);      //    524,288 B
  u16* qfrag  = (u16*)(ws + 35651584);      // 33,554,432 B
  u16* kfrag  = (u16*)(ws + 69206016);      // 33,554,432 B
  u16* vswb   = (u16*)(ws + 102760448);     // 33,554,432 B
  u16* attnb  = (u16*)(ws + 136314880);     // 33,554,432 B
  u16* bias2  = (u16*)(ws + 169869312);     //  2,097,152 B
  u16* mod2   = (u16*)(ws + 171966464);     //    131,072 B

  prep_kernel<<<4864, 256, 0, stream>>>(qkv_w, proj_w, rpb, qkvwb, projwb, bias2, mod2);
  gemm_bt<0><<<1536, 512, 0, stream>>>(x, nullptr, qkvwb, qkv_b,
                                       qfrag, kfrag, vswb, nullptr);
  attn_kernel<<<4096, 512, 0, stream>>>(qfrag, kfrag, vswb, bias2, mod2, attnb);
  gemm_bt<1><<<1024, 256, 0, stream>>>(nullptr, attnb, projwb, proj_b,
                                       nullptr, nullptr, nullptr, (float*)d_out);
}